// Round 7
// baseline (257.105 us; speedup 1.0000x reference)
//
#include <hip/hip_runtime.h>

#define DEV __device__ __forceinline__

typedef __attribute__((ext_vector_type(8))) _Float16 h8;
typedef __attribute__((ext_vector_type(4))) float f32x4;
typedef __attribute__((ext_vector_type(16))) float f32x16;
typedef __fp16 __attribute__((ext_vector_type(2))) hh2;

DEV unsigned short f2h(float f) {
  union { _Float16 h[2]; unsigned short u[2]; } v;
  v.h[0] = (_Float16)f;
  return v.u[0];
}

DEV void async_load16(const void* g, void* l) {
  __builtin_amdgcn_global_load_lds(
      (const __attribute__((address_space(1))) void*)g,
      (__attribute__((address_space(3))) void*)l,
      16, 0, 0);
}

// v_permlane32_swap_b32: a.row1 <-> b.row0 (exchanges the two 32-lane halves
// across two VGPRs). Both outputs are used (m214 T12 recipe).
DEV void pl32swap(unsigned int& a, unsigned int& b) {
  asm("v_permlane32_swap_b32 %0, %1" : "+v"(a), "+v"(b));
}

// LDS panel XOR swizzle (kept): row r, 16B col-block c stored at slot
// c ^ ((r>>1)&3); fragment reads use qs8 = (quad ^ ((ln>>1)&3))*8.

// ---------------------------------------------------------------- fused rmsnorm + q/kv projections (r14)
// prep is GONE: C[m,n] = inv[m] * sum_k (x[m,k]*g[k]) * w[n,k].
// A-staging loads RAW x/kv f32, multiplies g, casts f16 -> LDS, and
// accumulates per-row sumsq on the fly; inv[m] applied to the f32 acc in the
// epilogue (more accurate than the old f16 round-trip). qscale folds into the
// B cast. Weights reg-staged f32 -> f16 inline (L2/L3-resident re-reads).
// 128x128 tile, BK=64, 2-phase dbuf (r12-proven), LDS 64K+0.5K -> 2/CU.
__global__ __launch_bounds__(256, 2) void proj_fused(const float* __restrict__ x,
                                                     const float* __restrict__ kv,
                                                     const float* __restrict__ wq,
                                                     const float* __restrict__ wk,
                                                     const float* __restrict__ wv,
                                                     const float* __restrict__ gq,
                                                     const float* __restrict__ gkv,
                                                     unsigned short* __restrict__ qb,
                                                     unsigned short* __restrict__ kb,
                                                     unsigned short* __restrict__ vTb,
                                                     float qscale) {
  __shared__ __align__(16) unsigned short Al[2][2][128 * 32];
  __shared__ __align__(16) unsigned short Bl[2][2][128 * 32];
  __shared__ float invA[128];
  const int tid = threadIdx.x;
  const int w = tid >> 6, l = tid & 63;
  const int quad = l >> 4, ln = l & 15;
  const int wm0 = (w >> 1) * 64, wn0 = (w & 1) * 64;
  const int qs8 = (quad ^ ((l >> 1) & 3)) * 8;

  // staging geometry: thread covers A-row rA and B-row rA, k-half ch (32 f32)
  const int rA = tid >> 1;
  const int ch = tid & 1;
  const int swz = (rA >> 1) & 3;

  int z = blockIdx.x;
  const float *A, *W, *g;
  int m0, n0, isq;
  float wsc;
  if (z < 256) {
    A = x; g = gq; isq = 1; wsc = qscale;
    m0 = (((z >> 6) << 3) + (z & 7)) * 128;
    n0 = ((z >> 3) & 7) * 128;
    W = wq + (size_t)n0 * 1024;
  } else {
    z -= 256; A = kv; g = gkv; isq = 0; wsc = 1.0f;
    m0 = (((z >> 5) << 3) + (z & 7)) * 128;
    n0 = ((z >> 3) & 3) * 128;
    W = (n0 < 256) ? (wk + (size_t)n0 * 1024) : (wv + (size_t)(n0 - 256) * 1024);
  }

  f32x4 acc[4][4] = {};
  float ssq = 0.0f;

  auto stage = [&](int sb, int it) {
    const int kk = it * 64 + ch * 32;
    const float* ap = A + (size_t)(m0 + rA) * 1024 + kk;
    const float* bp = W + (size_t)rA * 1024 + kk;
    const float* gp = g + kk;
    float4 av[8], bv[8], gv[8];
#pragma unroll
    for (int i = 0; i < 8; ++i) av[i] = *(const float4*)(ap + i * 4);
#pragma unroll
    for (int i = 0; i < 8; ++i) bv[i] = *(const float4*)(bp + i * 4);
#pragma unroll
    for (int i = 0; i < 8; ++i) gv[i] = *(const float4*)(gp + i * 4);
#pragma unroll
    for (int i = 0; i < 8; ++i)
      ssq += av[i].x * av[i].x + av[i].y * av[i].y + av[i].z * av[i].z + av[i].w * av[i].w;
#pragma unroll
    for (int cb = 0; cb < 4; ++cb) {
      float4 a0 = av[2 * cb], a1 = av[2 * cb + 1];
      float4 g0 = gv[2 * cb], g1 = gv[2 * cb + 1];
      float4 b0 = bv[2 * cb], b1 = bv[2 * cb + 1];
      union { hh2 p[4]; h8 v; } ua, ub;
      ua.p[0] = __builtin_amdgcn_cvt_pkrtz(a0.x * g0.x, a0.y * g0.y);
      ua.p[1] = __builtin_amdgcn_cvt_pkrtz(a0.z * g0.z, a0.w * g0.w);
      ua.p[2] = __builtin_amdgcn_cvt_pkrtz(a1.x * g1.x, a1.y * g1.y);
      ua.p[3] = __builtin_amdgcn_cvt_pkrtz(a1.z * g1.z, a1.w * g1.w);
      ub.p[0] = __builtin_amdgcn_cvt_pkrtz(b0.x * wsc, b0.y * wsc);
      ub.p[1] = __builtin_amdgcn_cvt_pkrtz(b0.z * wsc, b0.w * wsc);
      ub.p[2] = __builtin_amdgcn_cvt_pkrtz(b1.x * wsc, b1.y * wsc);
      ub.p[3] = __builtin_amdgcn_cvt_pkrtz(b1.z * wsc, b1.w * wsc);
      const int sl = (cb ^ swz) * 8;
      *(h8*)&Al[sb][ch][rA * 32 + sl] = ua.v;
      *(h8*)&Bl[sb][ch][rA * 32 + sl] = ub.v;
    }
  };

  stage(0, 0);
  for (int it = 0; it < 16; ++it) {
    const int buf = it & 1;
    __syncthreads();
    if (it < 15) stage(buf ^ 1, it + 1);
#pragma unroll
    for (int kc = 0; kc < 2; ++kc) {
      h8 af[4], bf[4];
#pragma unroll
      for (int mi = 0; mi < 4; ++mi)
        af[mi] = *(const h8*)&Al[buf][kc][(wm0 + mi * 16 + ln) * 32 + qs8];
#pragma unroll
      for (int ni = 0; ni < 4; ++ni)
        bf[ni] = *(const h8*)&Bl[buf][kc][(wn0 + ni * 16 + ln) * 32 + qs8];
      __builtin_amdgcn_s_setprio(1);
#pragma unroll
      for (int mi = 0; mi < 4; ++mi)
#pragma unroll
        for (int ni = 0; ni < 4; ++ni)
          acc[mi][ni] = __builtin_amdgcn_mfma_f32_16x16x32_f16(af[mi], bf[ni], acc[mi][ni], 0, 0, 0);
      __builtin_amdgcn_s_setprio(0);
    }
  }

  // per-row inv scale: pair (rA,ch) and (rA,ch^1) hold the two k-halves
  ssq += __shfl_xor(ssq, 1);
  if (ch == 0) invA[rA] = rsqrtf(ssq * (1.0f / 1024.0f) + 1e-5f);
  __syncthreads();

#pragma unroll
  for (int mi = 0; mi < 4; ++mi)
#pragma unroll
    for (int ni = 0; ni < 4; ++ni)
#pragma unroll
      for (int r = 0; r < 4; ++r) {
        const int lr = wm0 + mi * 16 + quad * 4 + r;
        const int row = m0 + lr;
        const int col = n0 + wn0 + ni * 16 + ln;
        const unsigned short v = f2h(acc[mi][ni][r] * invA[lr]);
        if (isq) {
          qb[((size_t)row << 10) + col] = v;
        } else if (col < 256) {
          kb[(size_t)row * 256 + col] = v;
        } else {
          const int c2 = col - 256, gg = c2 >> 6, dd = c2 & 63;
          const int bb = row >> 11, t = row & 2047;
          vTb[((size_t)((bb * 4 + gg) * 64 + dd) << 11) + t] = v;
        }
      }
}

// ---------------------------------------------------------------- o projection (r14, fused wo cast) + residual
// r12 structure (2-phase dbuf, 128x128). B-panel now reg-stages RAW wo f32
// with inline cvt (wob intermediate gone). A-panel = (O0+O1)*Linv as before.
__global__ __launch_bounds__(256, 2) void o_fused(const unsigned short* __restrict__ O0,
                                                  const unsigned short* __restrict__ O1,
                                                  const float* __restrict__ l0p,
                                                  const float* __restrict__ l1p,
                                                  const float* __restrict__ wo,
                                                  const float* __restrict__ x,
                                                  float* __restrict__ out) {
  __shared__ __align__(16) unsigned short Al[2][2][128 * 32];
  __shared__ __align__(16) unsigned short Bl[2][2][128 * 32];
  __shared__ float Linv[16 * 128];
  const int tid = threadIdx.x;
  const int w = tid >> 6, l = tid & 63;
  const int quad = l >> 4, ln = l & 15;
  const int wm0 = (w >> 1) * 64, wn0 = (w & 1) * 64;
  const int qs8 = (quad ^ ((l >> 1) & 3)) * 8;

  const int z = blockIdx.x;
  const int m0 = (((z >> 6) << 3) + (z & 7)) * 128;
  const int n0 = ((z >> 3) & 7) * 128;

  // Linv[h][r] = 1/(l0+l1) for this block's 128 rows, all 16 heads
  {
    const int h = tid >> 4, r0 = (tid & 15) * 8;
#pragma unroll
    for (int i = 0; i < 8; ++i) {
      const int r = r0 + i;
      const size_t li = (size_t)(m0 + r) * 16 + h;
      Linv[h * 128 + r] = 1.0f / (l0p[li] + l1p[li]);
    }
  }
  __syncthreads();

  const int srow = tid >> 3;       // 0..31
  const int sp = (tid >> 2) & 1;   // col-half
  const int ss = tid & 3;          // 16B slot
  const int rB = tid >> 1;         // 0..127 (B staging row)
  const int ch = tid & 1;          // B k-half
  const int swzB = (rB >> 1) & 3;

  auto stageA = [&](int buf, int kk) {
    const int h = kk >> 6;
#pragma unroll
    for (int ps = 0; ps < 4; ++ps) {
      const int row = ps * 32 + srow;
      const size_t gidx = (size_t)(m0 + row) * 1024 + kk + sp * 32 + ss * 8;
      h8 a0 = *(const h8*)&O0[gidx];
      h8 a1 = *(const h8*)&O1[gidx];
      const _Float16 lv = (_Float16)Linv[h * 128 + row];
      h8 sum = a0 + a1;
#pragma unroll
      for (int q2 = 0; q2 < 8; ++q2) sum[q2] *= lv;
      const int sl = ss ^ ((row >> 1) & 3);
      *(h8*)&Al[buf][sp][row * 32 + sl * 8] = sum;
    }
  };
  auto stageB = [&](int buf, int kk) {
    const float* bp = wo + (size_t)(n0 + rB) * 1024 + kk + ch * 32;
    float4 bv[8];
#pragma unroll
    for (int i = 0; i < 8; ++i) bv[i] = *(const float4*)(bp + i * 4);
#pragma unroll
    for (int cb = 0; cb < 4; ++cb) {
      float4 b0 = bv[2 * cb], b1 = bv[2 * cb + 1];
      union { hh2 p[4]; h8 v; } ub;
      ub.p[0] = __builtin_amdgcn_cvt_pkrtz(b0.x, b0.y);
      ub.p[1] = __builtin_amdgcn_cvt_pkrtz(b0.z, b0.w);
      ub.p[2] = __builtin_amdgcn_cvt_pkrtz(b1.x, b1.y);
      ub.p[3] = __builtin_amdgcn_cvt_pkrtz(b1.z, b1.w);
      *(h8*)&Bl[buf][ch][rB * 32 + ((cb ^ swzB) * 8)] = ub.v;
    }
  };

  f32x4 acc[4][4] = {};
  stageB(0, 0);
  stageA(0, 0);
  for (int it = 0; it < 16; ++it) {
    const int buf = it & 1;
    __syncthreads();
    if (it < 15) { stageB(buf ^ 1, (it + 1) * 64); stageA(buf ^ 1, (it + 1) * 64); }
#pragma unroll
    for (int kc = 0; kc < 2; ++kc) {
      h8 af[4], bf[4];
#pragma unroll
      for (int mi = 0; mi < 4; ++mi)
        af[mi] = *(const h8*)&Al[buf][kc][(wm0 + mi * 16 + ln) * 32 + qs8];
#pragma unroll
      for (int ni = 0; ni < 4; ++ni)
        bf[ni] = *(const h8*)&Bl[buf][kc][(wn0 + ni * 16 + ln) * 32 + qs8];
      __builtin_amdgcn_s_setprio(1);
#pragma unroll
      for (int mi = 0; mi < 4; ++mi)
#pragma unroll
        for (int ni = 0; ni < 4; ++ni)
          acc[mi][ni] = __builtin_amdgcn_mfma_f32_16x16x32_f16(af[mi], bf[ni], acc[mi][ni], 0, 0, 0);
      __builtin_amdgcn_s_setprio(0);
    }
  }

#pragma unroll
  for (int mi = 0; mi < 4; ++mi)
#pragma unroll
    for (int ni = 0; ni < 4; ++ni)
#pragma unroll
      for (int r = 0; r < 4; ++r) {
        const int row = m0 + wm0 + mi * 16 + quad * 4 + r;
        const int col = n0 + wn0 + ni * 16 + ln;
        const size_t idx = ((size_t)row << 10) + col;
        out[idx] = x[idx] + acc[mi][ni][r];
      }
}

// ---------------------------------------------------------------- flash attention (r11, unchanged)
// 64 q-rows/wave: same kf/v fragments feed 32 MFMAs; counted-vmcnt
// triple-buffer (never vmcnt(0) mid-loop); in-register P via cvt_pk+permlane.
__global__ __launch_bounds__(256, 2) void flash_attn(const unsigned short* __restrict__ q,
                                                     const unsigned short* __restrict__ k,
                                                     const unsigned short* __restrict__ vT,
                                                     unsigned short* __restrict__ o0,
                                                     unsigned short* __restrict__ o1,
                                                     float* __restrict__ l0p,
                                                     float* __restrict__ l1p) {
  __shared__ __align__(16) unsigned short Kl[3][64 * 64];  // [t][d] f16, swizzled
  __shared__ __align__(16) unsigned short Vl[3][64 * 64];  // [d][t] f16 (V^T), swizzled

  const int tid = threadIdx.x;
  const int w = tid >> 6, l = tid & 63;
  const int lq = l & 31, hi = l >> 5;
  const int r8 = l >> 3, c8 = l & 7;
  const int csw = (c8 ^ r8) * 8;  // staging source swizzle (u16 units)
  const int rsw = lq & 7;
  const int s0 = blockIdx.x * 256;
  const int h = blockIdx.y, g = h >> 2;
  const int b = blockIdx.z >> 1, ts = blockIdx.z & 1;
  const int tbase = ts << 10;

  unsigned short* Opart = ts ? o1 : o0;
  float* lpart = ts ? l1p : l0p;

  // two q-rows per lane: q2 = 0,1
  size_t qrow[2];
  qrow[0] = (size_t)(b * 2048 + s0 + w * 64 + lq);
  qrow[1] = qrow[0] + 32;

  // Q B-fragments: lane holds Q[q=qrow[q2]][d = ks*16 + hi*8 + 0..7]
  h8 qf[2][4];
#pragma unroll
  for (int q2 = 0; q2 < 2; ++q2)
#pragma unroll
    for (int ks = 0; ks < 4; ++ks)
      qf[q2][ks] = *(const h8*)&q[(qrow[q2] << 10) + h * 64 + ks * 16 + hi * 8];
  // drain the q loads so the manual vmcnt bookkeeping below starts from 0
  asm volatile("s_waitcnt vmcnt(0)" ::: "memory");

  // per-lane LDS byte offsets shared by ALL K/V fragment reads (j = k-slot)
  int aoff[4];
#pragma unroll
  for (int j = 0; j < 4; ++j)
    aoff[j] = (lq * 64 + (((2 * j + hi) ^ rsw)) * 8) * 2;

  f32x16 oacc[2][2] = {};  // [q2][dblk]: O^T[d=dblk*32+crow(r,hi)][q=lq]
  float lsum[2] = {0.0f, 0.0f};

  const unsigned short* kbase = k + ((size_t)(b * 2048)) * 256 + g * 64;
  const unsigned short* vbase = vT + (((size_t)(b * 4 + g) * 64) << 11);

  const hh2 one2 = {(__fp16)1.0f, (__fp16)1.0f};

  auto stage = [&](int sb, int t0) {
#pragma unroll
    for (int j = 0; j < 2; ++j) {
      const int idx = w * 2 + j;  // 0..7 row-group of 8
      async_load16(kbase + (size_t)(t0 + idx * 8 + r8) * 256 + csw,
                   &Kl[sb][idx * 512]);
      async_load16(vbase + (((size_t)(idx * 8 + r8)) << 11) + t0 + csw,
                   &Vl[sb][idx * 512]);
    }
  };

#define FA_SYNC(N)                                                   \
  do {                                                               \
    asm volatile("s_waitcnt vmcnt(" #N ")" ::: "memory");            \
    __builtin_amdgcn_s_barrier();                                    \
    __builtin_amdgcn_sched_barrier(0);                               \
  } while (0)

// one t-half (32 t's) of one tile: shared kf feeds both q2 QK chains; shared
// v frags feed both q2 PV chains. All indices compile-time after unroll.
#define FA_HALF(CB, TH)                                                        \
  {                                                                            \
    h8 kf[4];                                                                  \
    _Pragma("unroll")                                                          \
    for (int ks = 0; ks < 4; ++ks)                                             \
      kf[ks] = *(const h8*)((const char*)&Kl[CB][(TH) * 2048] + aoff[ks]);     \
    f32x16 st0 = {}, st1 = {};                                                 \
    __builtin_amdgcn_s_setprio(1);                                             \
    _Pragma("unroll")                                                          \
    for (int ks = 0; ks < 4; ++ks) {                                           \
      st0 = __builtin_amdgcn_mfma_f32_32x32x16_f16(kf[ks], qf[0][ks], st0, 0, 0, 0); \
      st1 = __builtin_amdgcn_mfma_f32_32x32x16_f16(kf[ks], qf[1][ks], st1, 0, 0, 0); \
    }                                                                          \
    __builtin_amdgcn_s_setprio(0);                                             \
    unsigned int w0_[8], w1_[8];                                               \
    _Pragma("unroll")                                                          \
    for (int j = 0; j < 8; ++j) {                                              \
      union { hh2 h2; unsigned int u; } pk0, pk1;                              \
      pk0.h2 = __builtin_amdgcn_cvt_pkrtz(__builtin_amdgcn_exp2f(st0[2 * j]),  \
                                          __builtin_amdgcn_exp2f(st0[2 * j + 1])); \
      pk1.h2 = __builtin_amdgcn_cvt_pkrtz(__builtin_amdgcn_exp2f(st1[2 * j]),  \
                                          __builtin_amdgcn_exp2f(st1[2 * j + 1])); \
      lsum[0] = __builtin_amdgcn_fdot2(pk0.h2, one2, lsum[0], false);          \
      lsum[1] = __builtin_amdgcn_fdot2(pk1.h2, one2, lsum[1], false);          \
      w0_[j] = pk0.u; w1_[j] = pk1.u;                                          \
    }                                                                          \
    h8 pf0[2], pf1[2];                                                         \
    {                                                                          \
      unsigned int a0 = w0_[0], b0 = w0_[2]; pl32swap(a0, b0);                 \
      unsigned int a1 = w0_[1], b1 = w0_[3]; pl32swap(a1, b1);                 \
      unsigned int a4 = w0_[4], b4 = w0_[6]; pl32swap(a4, b4);                 \
      unsigned int a5 = w0_[5], b5 = w0_[7]; pl32swap(a5, b5);                 \
      union { unsigned int u[4]; h8 v; } f0, f1;                               \
      f0.u[0] = a0; f0.u[1] = a1; f0.u[2] = b0; f0.u[3] = b1;                  \
      f1.u[0] = a4; f1.u[1] = a5; f1.u[2] = b4; f1.u[3] = b5;                  \
      pf0[0] = f0.v; pf0[1] = f1.v;                                            \
      unsigned int c0 = w1_[0], d0 = w1_[2]; pl32swap(c0, d0);                 \
      unsigned int c1 = w1_[1], d1 = w1_[3]; pl32swap(c1, d1);                 \
      unsigned int c4 = w1_[4], d4 = w1_[6]; pl32swap(c4, d4);                 \
      unsigned int c5 = w1_[5], d5 = w1_[7]; pl32swap(c5, d5);                 \
      union { unsigned int u[4]; h8 v; } f2, f3;                               \
      f2.u[0] = c0; f2.u[1] = c1; f2.u[2] = d0; f2.u[3] = d1;                  \
      f3.u[0] = c4; f3.u[1] = c5; f3.u[2] = d4; f3.u[3] = d5;                  \
      pf1[0] = f2.v; pf1[1] = f3.v;                                            \
    }                                                                          \
    __builtin_amdgcn_s_setprio(1);                                             \
    _Pragma("unroll")                                                          \
    for (int cc = 0; cc < 2; ++cc) {                                           \
      const int c = (TH) * 2 + cc;                                             \
      h8 v0 = *(const h8*)((const char*)&Vl[CB][0] + aoff[c]);                 \
      h8 v1 = *(const h8*)((const char*)&Vl[CB][2048] + aoff[c]);              \
      oacc[0][0] = __builtin_amdgcn_mfma_f32_32x32x16_f16(v0, pf0[cc], oacc[0][0], 0, 0, 0); \
      oacc[1][0] = __builtin_amdgcn_mfma_f32_32x32x16_f16(v0, pf1[cc], oacc[1][0], 0, 0, 0); \
      oacc[0][1] = __builtin_amdgcn_mfma_f32_32x32x16_f16(v1, pf0[cc], oacc[0][1], 0, 0, 0); \
      oacc[1][1] = __builtin_amdgcn_mfma_f32_32x32x16_f16(v1, pf1[cc], oacc[1][1], 0, 0, 0); \
    }                                                                          \
    __builtin_amdgcn_s_setprio(0);                                             \
  }

#define FA_BODY(CB) { FA_HALF(CB, 0) FA_HALF(CB, 1) }

  // prologue: two tiles in flight
  stage(0, tbase);
  stage(1, tbase + 64);

  // main: t = 0..14 (vmcnt(4) uniform: tile t+1's 4 loads may stay in flight)
  for (int tt = 0; tt < 15; tt += 3) {
    FA_SYNC(4);
    stage(2, tbase + (tt + 2) * 64);
    FA_BODY(0);
    FA_SYNC(4);
    stage(0, tbase + (tt + 3) * 64);
    FA_BODY(1);
    FA_SYNC(4);
    if (tt + 4 < 16) stage(1, tbase + (tt + 4) * 64);
    FA_BODY(2);
  }
  // t = 15 (buffer 0)
  FA_SYNC(0);
  FA_BODY(0);

#undef FA_BODY
#undef FA_HALF
#undef FA_SYNC

  // lane l covers half the t's for q=lq; partner l^32 the other half
#pragma unroll
  for (int q2 = 0; q2 < 2; ++q2) {
    float ls = lsum[q2];
    ls += __shfl_xor(ls, 32);
    if (l < 32) lpart[qrow[q2] * 16 + h] = ls;
#pragma unroll
    for (int dblk = 0; dblk < 2; ++dblk)
#pragma unroll
      for (int qd = 0; qd < 4; ++qd) {
        ushort4 o;
        o.x = f2h(oacc[q2][dblk][qd * 4 + 0]);
        o.y = f2h(oacc[q2][dblk][qd * 4 + 1]);
        o.z = f2h(oacc[q2][dblk][qd * 4 + 2]);
        o.w = f2h(oacc[q2][dblk][qd * 4 + 3]);
        // d = dblk*32 + qd*8 + hi*4 + 0..3
        *(ushort4*)&Opart[(qrow[q2] << 10) + h * 64 + dblk * 32 + qd * 8 + hi * 4] = o;
      }
  }
}

// ---------------------------------------------------------------- launch (3 kernels)
extern "C" void kernel_launch(void* const* d_in, const int* in_sizes, int n_in,
                              void* d_out, int out_size, void* d_ws, size_t ws_size,
                              hipStream_t stream) {
  const float* x   = (const float*)d_in[0];
  const float* kv  = (const float*)d_in[1];
  const float* wq  = (const float*)d_in[2];
  const float* wk  = (const float*)d_in[3];
  const float* wv  = (const float*)d_in[4];
  const float* wo  = (const float*)d_in[5];
  const float* gq  = (const float*)d_in[6];
  const float* gkv = (const float*)d_in[7];

  char* ws = (char*)d_ws;
  unsigned short* O0  = (unsigned short*)(ws);               // 0-8M
  unsigned short* O1  = (unsigned short*)(ws + 8388608);     // 8-16M
  unsigned short* qb  = (unsigned short*)(ws + 16777216);    // 16-24M q f16 (pre-scaled)
  unsigned short* kb  = (unsigned short*)(ws + 25165824);    // 24-26M K f16 (4096x256)
  unsigned short* vTb = (unsigned short*)(ws + 27262976);    // 26-28M V^T f16
  float* l0p = (float*)(ws + 37748736);                      // 36M+ (256K)
  float* l1p = (float*)(ws + 38010880);                      // +256K

  const float qscale = 0.18033688011112042f;  // (1/8) * log2(e)

  // fused rmsnorm + q/kv projections (prep eliminated)
  proj_fused<<<384, 256, 0, stream>>>(x, kv, wq, wk, wv, gq, gkv, qb, kb, vTb, qscale);

  // flash: 256 Q-rows/block (64/wave), T-split 2 -> 512 blocks = 2/CU
  flash_attn<<<dim3(8, 16, 4), 256, 0, stream>>>(qb, kb, vTb, O0, O1, l0p, l1p);

  // o projection (fused wo cast + T-split combine + residual)
  o_fused<<<256, 256, 0, stream>>>(O0, O1, l0p, l1p, wo, x, (float*)d_out);
}

// Round 8
// 225.537 us; speedup vs baseline: 1.1400x; 1.1400x over previous
//
#include <hip/hip_runtime.h>

#define DEV __device__ __forceinline__

typedef __attribute__((ext_vector_type(8))) _Float16 h8;
typedef __attribute__((ext_vector_type(4))) float f32x4;
typedef __attribute__((ext_vector_type(16))) float f32x16;
typedef __fp16 __attribute__((ext_vector_type(2))) hh2;

DEV unsigned short f2h(float f) {
  union { _Float16 h[2]; unsigned short u[2]; } v;
  v.h[0] = (_Float16)f;
  return v.u[0];
}

DEV void async_load16(const void* g, void* l) {
  __builtin_amdgcn_global_load_lds(
      (const __attribute__((address_space(1))) void*)g,
      (__attribute__((address_space(3))) void*)l,
      16, 0, 0);
}

// v_permlane32_swap_b32: a.row1 <-> b.row0 (exchanges the two 32-lane halves
// across two VGPRs). Both outputs are used (m214 T12 recipe).
DEV void pl32swap(unsigned int& a, unsigned int& b) {
  asm("v_permlane32_swap_b32 %0, %1" : "+v"(a), "+v"(b));
}

// LDS panel XOR swizzle (kept): row r, 16B col-block c stored at slot
// c ^ ((r>>1)&3); fragment reads use qs8 = (quad ^ ((ln>>1)&3))*8.

// ---------------------------------------------------------------- prep (r12): wave-per-row rmsnorm
__global__ __launch_bounds__(256) void prep(const float* __restrict__ x,
                                            const float* __restrict__ kv,
                                            const float* __restrict__ wq,
                                            const float* __restrict__ wk,
                                            const float* __restrict__ wv,
                                            const float* __restrict__ wo,
                                            const float* __restrict__ gq,
                                            const float* __restrict__ gkv,
                                            unsigned short* __restrict__ wqb,
                                            unsigned short* __restrict__ wkvb,
                                            unsigned short* __restrict__ wob,
                                            unsigned short* __restrict__ xn,
                                            unsigned short* __restrict__ kvn,
                                            float qscale) {
  const int b = blockIdx.x, tid = threadIdx.x;
  if (b < 640) {
    // weight cast: 4096 floats per block
    const float* src;
    unsigned short* dst;
    float sc = 1.0f;
    int base;
    if (b < 256) { src = wq; dst = wqb; sc = qscale; base = b; }
    else if (b < 320) { src = wk; dst = wkvb; base = b - 256; }
    else if (b < 384) { src = wv; dst = wkvb + 262144; base = b - 320; }
    else { src = wo; dst = wob; base = b - 384; }
#pragma unroll
    for (int j = 0; j < 4; ++j) {
      const int i = base * 4096 + j * 1024 + tid * 4;
      float4 v = *(const float4*)&src[i];
      ushort4 o;
      o.x = f2h(v.x * sc); o.y = f2h(v.y * sc);
      o.z = f2h(v.z * sc); o.w = f2h(v.w * sc);
      *(ushort4*)&dst[i] = o;
    }
    return;
  }
  // rmsnorm: one wave per 1024-elem row
  const int w = tid >> 6, l = tid & 63;
  int row = (b - 640) * 4 + w;
  const float* src;
  const float* g;
  unsigned short* dst;
  if (row < 4096) { src = x; g = gq; dst = xn; }
  else { row -= 4096; src = kv; g = gkv; dst = kvn; }
  const float* xr = src + (size_t)row * 1024;
  float4 v[4];
  float ss = 0.0f;
#pragma unroll
  for (int i = 0; i < 4; ++i) {
    v[i] = *(const float4*)&xr[i * 256 + l * 4];
    ss += v[i].x * v[i].x + v[i].y * v[i].y + v[i].z * v[i].z + v[i].w * v[i].w;
  }
  ss += __shfl_xor(ss, 32); ss += __shfl_xor(ss, 16);
  ss += __shfl_xor(ss, 8);  ss += __shfl_xor(ss, 4);
  ss += __shfl_xor(ss, 2);  ss += __shfl_xor(ss, 1);
  const float inv = rsqrtf(ss * (1.0f / 1024.0f) + 1e-5f);
#pragma unroll
  for (int i = 0; i < 4; ++i) {
    float4 gv = *(const float4*)&g[i * 256 + l * 4];
    ushort4 o;
    o.x = f2h(v[i].x * inv * gv.x); o.y = f2h(v[i].y * inv * gv.y);
    o.z = f2h(v[i].z * inv * gv.z); o.w = f2h(v[i].w * inv * gv.w);
    *(ushort4*)&dst[(size_t)row * 1024 + i * 256 + l * 4] = o;
  }
}

// ---------------------------------------------------------------- fused q + kv projections (r12 exact)
// 128x128 tile, 4 waves x 64x64, BK=64, 2-phase dbuf, swizzled, XCD-mapped.
__global__ __launch_bounds__(256, 2) void proj_gemm(const unsigned short* __restrict__ xn,
                                                    const unsigned short* __restrict__ kvn,
                                                    const unsigned short* __restrict__ wqb,
                                                    const unsigned short* __restrict__ wkvb,
                                                    unsigned short* __restrict__ qb,
                                                    unsigned short* __restrict__ kb,
                                                    unsigned short* __restrict__ vTb) {
  __shared__ unsigned short Al[2][2][128 * 32];
  __shared__ unsigned short Bl[2][2][128 * 32];
  const int tid = threadIdx.x;
  const int w = tid >> 6, l = tid & 63;
  const int quad = l >> 4, ln = l & 15;
  const int wm0 = (w >> 1) * 64, wn0 = (w & 1) * 64;
  const int r4 = l >> 2;
  const int c4s = (((l & 3) ^ ((l >> 3) & 3))) * 8;
  const int qs8 = (quad ^ ((l >> 1) & 3)) * 8;

  int z = blockIdx.x;
  const unsigned short *A, *W;
  int m0, n0, isq;
  if (z < 256) {
    A = xn; W = wqb; isq = 1;
    m0 = (((z >> 6) << 3) + (z & 7)) * 128;
    n0 = ((z >> 3) & 7) * 128;
  } else {
    z -= 256; A = kvn; W = wkvb; isq = 0;
    m0 = (((z >> 5) << 3) + (z & 7)) * 128;
    n0 = ((z >> 3) & 3) * 128;
  }

  f32x4 acc[4][4] = {};

  auto stage = [&](int buf, int kk) {
#pragma unroll
    for (int j = 0; j < 8; ++j) {
      const int idx = w * 8 + j;
      if (idx < 16) {
        const int p = idx >> 3, rb = (idx & 7) * 16;
        async_load16(A + (size_t)(m0 + rb + r4) * 1024 + kk + p * 32 + c4s,
                     &Al[buf][p][rb * 32]);
      } else {
        const int ib = idx - 16;
        const int p = ib >> 3, rb = (ib & 7) * 16;
        async_load16(W + (size_t)(n0 + rb + r4) * 1024 + kk + p * 32 + c4s,
                     &Bl[buf][p][rb * 32]);
      }
    }
  };

  stage(0, 0);
  for (int it = 0; it < 16; ++it) {
    const int buf = it & 1;
    __syncthreads();
    if (it < 15) stage(buf ^ 1, (it + 1) * 64);
#pragma unroll
    for (int kc = 0; kc < 2; ++kc) {
      h8 af[4], bf[4];
#pragma unroll
      for (int mi = 0; mi < 4; ++mi)
        af[mi] = *(const h8*)&Al[buf][kc][(wm0 + mi * 16 + ln) * 32 + qs8];
#pragma unroll
      for (int ni = 0; ni < 4; ++ni)
        bf[ni] = *(const h8*)&Bl[buf][kc][(wn0 + ni * 16 + ln) * 32 + qs8];
#pragma unroll
      for (int mi = 0; mi < 4; ++mi)
#pragma unroll
        for (int ni = 0; ni < 4; ++ni)
          acc[mi][ni] = __builtin_amdgcn_mfma_f32_16x16x32_f16(af[mi], bf[ni], acc[mi][ni], 0, 0, 0);
    }
  }

#pragma unroll
  for (int mi = 0; mi < 4; ++mi)
#pragma unroll
    for (int ni = 0; ni < 4; ++ni)
#pragma unroll
      for (int r = 0; r < 4; ++r) {
        const int row = m0 + wm0 + mi * 16 + quad * 4 + r;
        const int col = n0 + wn0 + ni * 16 + ln;
        const unsigned short v = f2h(acc[mi][ni][r]);
        if (isq) {
          qb[((size_t)row << 10) + col] = v;
        } else if (col < 256) {
          kb[(size_t)row * 256 + col] = v;
        } else {
          const int c2 = col - 256, gg = c2 >> 6, dd = c2 & 63;
          const int bb = row >> 11, t = row & 2047;
          vTb[((size_t)((bb * 4 + gg) * 64 + dd) << 11) + t] = v;
        }
      }
}

// ---------------------------------------------------------------- o projection (r12 + 3-way combine) + residual
__global__ __launch_bounds__(256) void o_gemm(const unsigned short* __restrict__ O0,
                                              const unsigned short* __restrict__ O1,
                                              const unsigned short* __restrict__ O2,
                                              const float* __restrict__ l0p,
                                              const float* __restrict__ l1p,
                                              const float* __restrict__ l2p,
                                              const unsigned short* __restrict__ wob,
                                              const float* __restrict__ x,
                                              float* __restrict__ out) {
  __shared__ unsigned short Al[2][2][128 * 32];
  __shared__ unsigned short Bl[2][2][128 * 32];
  __shared__ float Linv[16 * 128];
  const int tid = threadIdx.x;
  const int w = tid >> 6, l = tid & 63;
  const int quad = l >> 4, ln = l & 15;
  const int wm0 = (w >> 1) * 64, wn0 = (w & 1) * 64;
  const int r4 = l >> 2;
  const int c4s = (((l & 3) ^ ((l >> 3) & 3))) * 8;
  const int qs8 = (quad ^ ((l >> 1) & 3)) * 8;

  const int z = blockIdx.x;
  const int m0 = (((z >> 6) << 3) + (z & 7)) * 128;
  const int n0 = ((z >> 3) & 7) * 128;

  // Linv[h][r] = 1/(l0+l1+l2) for this block's 128 rows, all 16 heads
  {
    const int h = tid >> 4, r0 = (tid & 15) * 8;
#pragma unroll
    for (int i = 0; i < 8; ++i) {
      const int r = r0 + i;
      const size_t li = (size_t)(m0 + r) * 16 + h;
      Linv[h * 128 + r] = 1.0f / (l0p[li] + l1p[li] + l2p[li]);
    }
  }
  __syncthreads();

  const int srow = tid >> 3;       // 0..31
  const int sp = (tid >> 2) & 1;   // col-half
  const int ss = tid & 3;          // 16B slot

  auto stageA = [&](int buf, int kk) {
    const int h = kk >> 6;
#pragma unroll
    for (int ps = 0; ps < 4; ++ps) {
      const int row = ps * 32 + srow;
      const size_t gidx = (size_t)(m0 + row) * 1024 + kk + sp * 32 + ss * 8;
      h8 a0 = *(const h8*)&O0[gidx];
      h8 a1 = *(const h8*)&O1[gidx];
      h8 a2 = *(const h8*)&O2[gidx];
      const _Float16 lv = (_Float16)Linv[h * 128 + row];
      h8 sum = a0 + a1 + a2;
#pragma unroll
      for (int q2 = 0; q2 < 8; ++q2) sum[q2] *= lv;
      const int sl = ss ^ ((row >> 1) & 3);
      *(h8*)&Al[buf][sp][row * 32 + sl * 8] = sum;
    }
  };
  auto stageB = [&](int buf, int kk) {
#pragma unroll
    for (int j = 0; j < 4; ++j) {
      const int ib = w * 4 + j;
      const int p = ib >> 3, rb = (ib & 7) * 16;
      async_load16(wob + (size_t)(n0 + rb + r4) * 1024 + kk + p * 32 + c4s,
                   &Bl[buf][p][rb * 32]);
    }
  };

  f32x4 acc[4][4] = {};
  stageB(0, 0);
  stageA(0, 0);
  for (int it = 0; it < 16; ++it) {
    const int buf = it & 1;
    __syncthreads();
    if (it < 15) { stageB(buf ^ 1, (it + 1) * 64); stageA(buf ^ 1, (it + 1) * 64); }
#pragma unroll
    for (int kc = 0; kc < 2; ++kc) {
      h8 af[4], bf[4];
#pragma unroll
      for (int mi = 0; mi < 4; ++mi)
        af[mi] = *(const h8*)&Al[buf][kc][(wm0 + mi * 16 + ln) * 32 + qs8];
#pragma unroll
      for (int ni = 0; ni < 4; ++ni)
        bf[ni] = *(const h8*)&Bl[buf][kc][(wn0 + ni * 16 + ln) * 32 + qs8];
#pragma unroll
      for (int mi = 0; mi < 4; ++mi)
#pragma unroll
        for (int ni = 0; ni < 4; ++ni)
          acc[mi][ni] = __builtin_amdgcn_mfma_f32_16x16x32_f16(af[mi], bf[ni], acc[mi][ni], 0, 0, 0);
    }
  }

#pragma unroll
  for (int mi = 0; mi < 4; ++mi)
#pragma unroll
    for (int ni = 0; ni < 4; ++ni)
#pragma unroll
      for (int r = 0; r < 4; ++r) {
        const int row = m0 + wm0 + mi * 16 + quad * 4 + r;
        const int col = n0 + wn0 + ni * 16 + ln;
        const size_t idx = ((size_t)row << 10) + col;
        out[idx] = x[idx] + acc[mi][ni][r];
      }
}

// ---------------------------------------------------------------- flash attention (r15: T-split 3)
// r11 structure (64 q-rows/wave, in-register P, counted-vmcnt triple-buffer)
// with T-split 2 -> 3: flash was GRID-limited at 2 blocks/CU (512 blocks) while
// being latency-bound (per-iter pipe demand ~2.3k cyc of 7.3k actual). Parts
// of 11/11/10 K/V-tiles -> 768 blocks = 3/CU = 12 waves/CU (LDS 144K fits).
// Pipeline guards are uniform scalar branches; tail body uses runtime buffer.
__global__ __launch_bounds__(256, 3) void flash_attn(const unsigned short* __restrict__ q,
                                                     const unsigned short* __restrict__ k,
                                                     const unsigned short* __restrict__ vT,
                                                     unsigned short* __restrict__ o0,
                                                     unsigned short* __restrict__ o1,
                                                     unsigned short* __restrict__ o2,
                                                     float* __restrict__ l0p,
                                                     float* __restrict__ l1p,
                                                     float* __restrict__ l2p) {
  __shared__ __align__(16) unsigned short Kl[3][64 * 64];  // [t][d] f16, swizzled
  __shared__ __align__(16) unsigned short Vl[3][64 * 64];  // [d][t] f16 (V^T), swizzled

  const int tid = threadIdx.x;
  const int w = tid >> 6, l = tid & 63;
  const int lq = l & 31, hi = l >> 5;
  const int r8 = l >> 3, c8 = l & 7;
  const int csw = (c8 ^ r8) * 8;  // staging source swizzle (u16 units)
  const int rsw = lq & 7;
  const int s0 = blockIdx.x * 256;
  const int h = blockIdx.y, g = h >> 2;
  const int zz = blockIdx.z;          // 0..5
  const int b = zz / 3, ts = zz - b * 3;
  const int nt = (ts == 2) ? 10 : 11; // tiles per part (11+11+10 = 32)
  const int tbase = ts * 704;         // 0, 704, 1408

  unsigned short* Opart = (ts == 0) ? o0 : (ts == 1) ? o1 : o2;
  float* lpart = (ts == 0) ? l0p : (ts == 1) ? l1p : l2p;

  // two q-rows per lane: q2 = 0,1
  size_t qrow[2];
  qrow[0] = (size_t)(b * 2048 + s0 + w * 64 + lq);
  qrow[1] = qrow[0] + 32;

  // Q B-fragments: lane holds Q[q=qrow[q2]][d = ks*16 + hi*8 + 0..7]
  h8 qf[2][4];
#pragma unroll
  for (int q2 = 0; q2 < 2; ++q2)
#pragma unroll
    for (int ks = 0; ks < 4; ++ks)
      qf[q2][ks] = *(const h8*)&q[(qrow[q2] << 10) + h * 64 + ks * 16 + hi * 8];
  // drain the q loads so the manual vmcnt bookkeeping below starts from 0
  asm volatile("s_waitcnt vmcnt(0)" ::: "memory");

  // per-lane LDS byte offsets shared by ALL K/V fragment reads (j = k-slot)
  int aoff[4];
#pragma unroll
  for (int j = 0; j < 4; ++j)
    aoff[j] = (lq * 64 + (((2 * j + hi) ^ rsw)) * 8) * 2;

  f32x16 oacc[2][2] = {};  // [q2][dblk]: O^T[d=dblk*32+crow(r,hi)][q=lq]
  float lsum[2] = {0.0f, 0.0f};

  const unsigned short* kbase = k + ((size_t)(b * 2048)) * 256 + g * 64;
  const unsigned short* vbase = vT + (((size_t)(b * 4 + g) * 64) << 11);

  const hh2 one2 = {(__fp16)1.0f, (__fp16)1.0f};

  auto stage = [&](int sb, int t0) {
#pragma unroll
    for (int j = 0; j < 2; ++j) {
      const int idx = w * 2 + j;  // 0..7 row-group of 8
      async_load16(kbase + (size_t)(t0 + idx * 8 + r8) * 256 + csw,
                   &Kl[sb][idx * 512]);
      async_load16(vbase + (((size_t)(idx * 8 + r8)) << 11) + t0 + csw,
                   &Vl[sb][idx * 512]);
    }
  };

#define FA_SYNC(N)                                                   \
  do {                                                               \
    asm volatile("s_waitcnt vmcnt(" #N ")" ::: "memory");            \
    __builtin_amdgcn_s_barrier();                                    \
    __builtin_amdgcn_sched_barrier(0);                               \
  } while (0)

// one t-half (32 t's) of one tile, base pointers KB/VB (LDS): shared kf feeds
// both q2 QK chains; shared v frags feed both q2 PV chains.
#define FA_HALF(KB, VB, TH)                                                    \
  {                                                                            \
    h8 kf[4];                                                                  \
    _Pragma("unroll")                                                          \
    for (int ks = 0; ks < 4; ++ks)                                             \
      kf[ks] = *(const h8*)((const char*)(KB) + (TH) * 4096 + aoff[ks]);       \
    f32x16 st0 = {}, st1 = {};                                                 \
    __builtin_amdgcn_s_setprio(1);                                             \
    _Pragma("unroll")                                                          \
    for (int ks = 0; ks < 4; ++ks) {                                           \
      st0 = __builtin_amdgcn_mfma_f32_32x32x16_f16(kf[ks], qf[0][ks], st0, 0, 0, 0); \
      st1 = __builtin_amdgcn_mfma_f32_32x32x16_f16(kf[ks], qf[1][ks], st1, 0, 0, 0); \
    }                                                                          \
    __builtin_amdgcn_s_setprio(0);                                             \
    unsigned int w0_[8], w1_[8];                                               \
    _Pragma("unroll")                                                          \
    for (int j = 0; j < 8; ++j) {                                              \
      union { hh2 h2; unsigned int u; } pk0, pk1;                              \
      pk0.h2 = __builtin_amdgcn_cvt_pkrtz(__builtin_amdgcn_exp2f(st0[2 * j]),  \
                                          __builtin_amdgcn_exp2f(st0[2 * j + 1])); \
      pk1.h2 = __builtin_amdgcn_cvt_pkrtz(__builtin_amdgcn_exp2f(st1[2 * j]),  \
                                          __builtin_amdgcn_exp2f(st1[2 * j + 1])); \
      lsum[0] = __builtin_amdgcn_fdot2(pk0.h2, one2, lsum[0], false);          \
      lsum[1] = __builtin_amdgcn_fdot2(pk1.h2, one2, lsum[1], false);          \
      w0_[j] = pk0.u; w1_[j] = pk1.u;                                          \
    }                                                                          \
    h8 pf0[2], pf1[2];                                                         \
    {                                                                          \
      unsigned int a0 = w0_[0], b0 = w0_[2]; pl32swap(a0, b0);                 \
      unsigned int a1 = w0_[1], b1 = w0_[3]; pl32swap(a1, b1);                 \
      unsigned int a4 = w0_[4], b4 = w0_[6]; pl32swap(a4, b4);                 \
      unsigned int a5 = w0_[5], b5 = w0_[7]; pl32swap(a5, b5);                 \
      union { unsigned int u[4]; h8 v; } f0, f1;                               \
      f0.u[0] = a0; f0.u[1] = a1; f0.u[2] = b0; f0.u[3] = b1;                  \
      f1.u[0] = a4; f1.u[1] = a5; f1.u[2] = b4; f1.u[3] = b5;                  \
      pf0[0] = f0.v; pf0[1] = f1.v;                                            \
      unsigned int c0 = w1_[0], d0 = w1_[2]; pl32swap(c0, d0);                 \
      unsigned int c1 = w1_[1], d1 = w1_[3]; pl32swap(c1, d1);                 \
      unsigned int c4 = w1_[4], d4 = w1_[6]; pl32swap(c4, d4);                 \
      unsigned int c5 = w1_[5], d5 = w1_[7]; pl32swap(c5, d5);                 \
      union { unsigned int u[4]; h8 v; } f2, f3;                               \
      f2.u[0] = c0; f2.u[1] = c1; f2.u[2] = d0; f2.u[3] = d1;                  \
      f3.u[0] = c4; f3.u[1] = c5; f3.u[2] = d4; f3.u[3] = d5;                  \
      pf1[0] = f2.v; pf1[1] = f3.v;                                            \
    }                                                                          \
    __builtin_amdgcn_s_setprio(1);                                             \
    _Pragma("unroll")                                                          \
    for (int cc = 0; cc < 2; ++cc) {                                           \
      const int c = (TH) * 2 + cc;                                             \
      h8 v0 = *(const h8*)((const char*)(VB) + aoff[c]);                       \
      h8 v1 = *(const h8*)((const char*)(VB) + 4096 + aoff[c]);                \
      oacc[0][0] = __builtin_amdgcn_mfma_f32_32x32x16_f16(v0, pf0[cc], oacc[0][0], 0, 0, 0); \
      oacc[1][0] = __builtin_amdgcn_mfma_f32_32x32x16_f16(v0, pf1[cc], oacc[1][0], 0, 0, 0); \
      oacc[0][1] = __builtin_amdgcn_mfma_f32_32x32x16_f16(v1, pf0[cc], oacc[0][1], 0, 0, 0); \
      oacc[1][1] = __builtin_amdgcn_mfma_f32_32x32x16_f16(v1, pf1[cc], oacc[1][1], 0, 0, 0); \
    }                                                                          \
    __builtin_amdgcn_s_setprio(0);                                             \
  }

#define FA_BODY(CB) { FA_HALF(&Kl[CB][0], &Vl[CB][0], 0) FA_HALF(&Kl[CB][0], &Vl[CB][0], 1) }

  // prologue: two tiles in flight (nt >= 10 always)
  stage(0, tbase);
  stage(1, tbase + 64);

  // main: bodies 0..nt-2 (vmcnt(4): next tile's 4 loads may stay in flight);
  // guards are block-uniform scalars. Tail body nt-1 handled after the loop.
  for (int tt = 0; tt + 1 < nt; tt += 3) {
    FA_SYNC(4);
    if (tt + 2 < nt) stage(2, tbase + (tt + 2) * 64);
    FA_BODY(0);
    if (tt + 2 < nt) {
      FA_SYNC(4);
      if (tt + 3 < nt) stage(0, tbase + (tt + 3) * 64);
      FA_BODY(1);
      if (tt + 3 < nt) {
        FA_SYNC(4);
        if (tt + 4 < nt) stage(1, tbase + (tt + 4) * 64);
        FA_BODY(2);
      }
    }
  }
  // tail: body nt-1, buffer (nt-1)%3 (= 1 for nt=11, 0 for nt=10)
  {
    const int cbt = (ts == 2) ? 0 : 1;
    const unsigned short* KB = &Kl[cbt][0];
    const unsigned short* VB = &Vl[cbt][0];
    FA_SYNC(0);
    FA_HALF(KB, VB, 0)
    FA_HALF(KB, VB, 1)
  }

#undef FA_BODY
#undef FA_HALF
#undef FA_SYNC

  // lane l covers half the t's for q=lq; partner l^32 the other half
#pragma unroll
  for (int q2 = 0; q2 < 2; ++q2) {
    float ls = lsum[q2];
    ls += __shfl_xor(ls, 32);
    if (l < 32) lpart[qrow[q2] * 16 + h] = ls;
#pragma unroll
    for (int dblk = 0; dblk < 2; ++dblk)
#pragma unroll
      for (int qd = 0; qd < 4; ++qd) {
        ushort4 o;
        o.x = f2h(oacc[q2][dblk][qd * 4 + 0]);
        o.y = f2h(oacc[q2][dblk][qd * 4 + 1]);
        o.z = f2h(oacc[q2][dblk][qd * 4 + 2]);
        o.w = f2h(oacc[q2][dblk][qd * 4 + 3]);
        // d = dblk*32 + qd*8 + hi*4 + 0..3
        *(ushort4*)&Opart[(qrow[q2] << 10) + h * 64 + dblk * 32 + qd * 8 + hi * 4] = o;
      }
  }
}

// ---------------------------------------------------------------- launch
extern "C" void kernel_launch(void* const* d_in, const int* in_sizes, int n_in,
                              void* d_out, int out_size, void* d_ws, size_t ws_size,
                              hipStream_t stream) {
  const float* x   = (const float*)d_in[0];
  const float* kv  = (const float*)d_in[1];
  const float* wq  = (const float*)d_in[2];
  const float* wk  = (const float*)d_in[3];
  const float* wv  = (const float*)d_in[4];
  const float* wo  = (const float*)d_in[5];
  const float* gq  = (const float*)d_in[6];
  const float* gkv = (const float*)d_in[7];

  char* ws = (char*)d_ws;
  unsigned short* xn   = (unsigned short*)(ws);              // 0-8M   xn -> Opart0
  unsigned short* kvn  = (unsigned short*)(ws + 8388608);    // 8-16M  kvn -> Opart1
  unsigned short* qb   = (unsigned short*)(ws + 16777216);   // 16-24M q f16 (pre-scaled)
  unsigned short* kb   = (unsigned short*)(ws + 25165824);   // 24-26M K f16 (4096x256)
  unsigned short* vTb  = (unsigned short*)(ws + 27262976);   // 26-28M V^T f16
  unsigned short* O2   = (unsigned short*)(ws + 29360128);   // 28-36M (the former hole)
  unsigned short* wqb  = (unsigned short*)(ws + 37748736);   // 36-38M wq f16 -> l0p/l1p/l2p
  unsigned short* wkvb = (unsigned short*)(ws + 39845888);   // 38-39M [wk;wv] f16
  unsigned short* wob  = (unsigned short*)(ws + 40894464);   // 39-41M wo f16
  unsigned short* Opart0 = xn;
  unsigned short* Opart1 = kvn;
  float* l0p = (float*)wqb;
  float* l1p = (float*)(ws + 37748736 + 262144);
  float* l2p = (float*)(ws + 37748736 + 524288);

  const float qscale = 0.18033688011112042f;  // (1/8) * log2(e)

  prep<<<2688, 256, 0, stream>>>(x, kv, wq, wk, wv, wo, gq, gkv,
                                 wqb, wkvb, wob, xn, kvn, qscale);

  // fused q + kv projections (128x128 tiles, dbuf, swizzled, XCD-mapped)
  proj_gemm<<<384, 256, 0, stream>>>(xn, kvn, wqb, wkvb, qb, kb, vTb);

  // flash: 256 Q-rows/block (64/wave), T-split 3 -> 768 blocks = 3/CU
  flash_attn<<<dim3(8, 16, 6), 256, 0, stream>>>(qb, kb, vTb, Opart0, Opart1, O2,
                                                 l0p, l1p, l2p);

  // o projection (128x128) with fused 3-way T-split combine + residual
  o_gemm<<<256, 256, 0, stream>>>(Opart0, Opart1, O2, l0p, l1p, l2p, wob, x, (float*)d_out);
}

// Round 9
// 198.401 us; speedup vs baseline: 1.2959x; 1.1368x over previous
//
#include <hip/hip_runtime.h>

#define DEV __device__ __forceinline__

typedef __attribute__((ext_vector_type(8))) _Float16 h8;
typedef __attribute__((ext_vector_type(4))) float f32x4;
typedef __attribute__((ext_vector_type(16))) float f32x16;
typedef __fp16 __attribute__((ext_vector_type(2))) hh2;

DEV unsigned short f2h(float f) {
  union { _Float16 h[2]; unsigned short u[2]; } v;
  v.h[0] = (_Float16)f;
  return v.u[0];
}

DEV void async_load16(const void* g, void* l) {
  __builtin_amdgcn_global_load_lds(
      (const __attribute__((address_space(1))) void*)g,
      (__attribute__((address_space(3))) void*)l,
      16, 0, 0);
}

// v_permlane32_swap_b32: a.row1 <-> b.row0 (exchanges the two 32-lane halves
// across two VGPRs). Both outputs are used (m214 T12 recipe).
DEV void pl32swap(unsigned int& a, unsigned int& b) {
  asm("v_permlane32_swap_b32 %0, %1" : "+v"(a), "+v"(b));
}

// LDS panel XOR swizzle (kept): row r, 16B col-block c stored at slot
// c ^ ((r>>1)&3); fragment reads use qs8 = (quad ^ ((ln>>1)&3))*8.

// ---------------------------------------------------------------- prep (r12): wave-per-row rmsnorm
__global__ __launch_bounds__(256) void prep(const float* __restrict__ x,
                                            const float* __restrict__ kv,
                                            const float* __restrict__ wq,
                                            const float* __restrict__ wk,
                                            const float* __restrict__ wv,
                                            const float* __restrict__ wo,
                                            const float* __restrict__ gq,
                                            const float* __restrict__ gkv,
                                            unsigned short* __restrict__ wqb,
                                            unsigned short* __restrict__ wkvb,
                                            unsigned short* __restrict__ wob,
                                            unsigned short* __restrict__ xn,
                                            unsigned short* __restrict__ kvn,
                                            float qscale) {
  const int b = blockIdx.x, tid = threadIdx.x;
  if (b < 640) {
    // weight cast: 4096 floats per block
    const float* src;
    unsigned short* dst;
    float sc = 1.0f;
    int base;
    if (b < 256) { src = wq; dst = wqb; sc = qscale; base = b; }
    else if (b < 320) { src = wk; dst = wkvb; base = b - 256; }
    else if (b < 384) { src = wv; dst = wkvb + 262144; base = b - 320; }
    else { src = wo; dst = wob; base = b - 384; }
#pragma unroll
    for (int j = 0; j < 4; ++j) {
      const int i = base * 4096 + j * 1024 + tid * 4;
      float4 v = *(const float4*)&src[i];
      ushort4 o;
      o.x = f2h(v.x * sc); o.y = f2h(v.y * sc);
      o.z = f2h(v.z * sc); o.w = f2h(v.w * sc);
      *(ushort4*)&dst[i] = o;
    }
    return;
  }
  // rmsnorm: one wave per 1024-elem row
  const int w = tid >> 6, l = tid & 63;
  int row = (b - 640) * 4 + w;
  const float* src;
  const float* g;
  unsigned short* dst;
  if (row < 4096) { src = x; g = gq; dst = xn; }
  else { row -= 4096; src = kv; g = gkv; dst = kvn; }
  const float* xr = src + (size_t)row * 1024;
  float4 v[4];
  float ss = 0.0f;
#pragma unroll
  for (int i = 0; i < 4; ++i) {
    v[i] = *(const float4*)&xr[i * 256 + l * 4];
    ss += v[i].x * v[i].x + v[i].y * v[i].y + v[i].z * v[i].z + v[i].w * v[i].w;
  }
  ss += __shfl_xor(ss, 32); ss += __shfl_xor(ss, 16);
  ss += __shfl_xor(ss, 8);  ss += __shfl_xor(ss, 4);
  ss += __shfl_xor(ss, 2);  ss += __shfl_xor(ss, 1);
  const float inv = rsqrtf(ss * (1.0f / 1024.0f) + 1e-5f);
#pragma unroll
  for (int i = 0; i < 4; ++i) {
    float4 gv = *(const float4*)&g[i * 256 + l * 4];
    ushort4 o;
    o.x = f2h(v[i].x * inv * gv.x); o.y = f2h(v[i].y * inv * gv.y);
    o.z = f2h(v[i].z * inv * gv.z); o.w = f2h(v[i].w * inv * gv.w);
    *(ushort4*)&dst[(size_t)row * 1024 + i * 256 + l * 4] = o;
  }
}

// ---------------------------------------------------------------- fused q + kv projections (r12 exact)
// 128x128 tile, 4 waves x 64x64, BK=64, 2-phase dbuf, swizzled, XCD-mapped.
__global__ __launch_bounds__(256, 2) void proj_gemm(const unsigned short* __restrict__ xn,
                                                    const unsigned short* __restrict__ kvn,
                                                    const unsigned short* __restrict__ wqb,
                                                    const unsigned short* __restrict__ wkvb,
                                                    unsigned short* __restrict__ qb,
                                                    unsigned short* __restrict__ kb,
                                                    unsigned short* __restrict__ vTb) {
  __shared__ unsigned short Al[2][2][128 * 32];
  __shared__ unsigned short Bl[2][2][128 * 32];
  const int tid = threadIdx.x;
  const int w = tid >> 6, l = tid & 63;
  const int quad = l >> 4, ln = l & 15;
  const int wm0 = (w >> 1) * 64, wn0 = (w & 1) * 64;
  const int r4 = l >> 2;
  const int c4s = (((l & 3) ^ ((l >> 3) & 3))) * 8;
  const int qs8 = (quad ^ ((l >> 1) & 3)) * 8;

  int z = blockIdx.x;
  const unsigned short *A, *W;
  int m0, n0, isq;
  if (z < 256) {
    A = xn; W = wqb; isq = 1;
    m0 = (((z >> 6) << 3) + (z & 7)) * 128;
    n0 = ((z >> 3) & 7) * 128;
  } else {
    z -= 256; A = kvn; W = wkvb; isq = 0;
    m0 = (((z >> 5) << 3) + (z & 7)) * 128;
    n0 = ((z >> 3) & 3) * 128;
  }

  f32x4 acc[4][4] = {};

  auto stage = [&](int buf, int kk) {
#pragma unroll
    for (int j = 0; j < 8; ++j) {
      const int idx = w * 8 + j;
      if (idx < 16) {
        const int p = idx >> 3, rb = (idx & 7) * 16;
        async_load16(A + (size_t)(m0 + rb + r4) * 1024 + kk + p * 32 + c4s,
                     &Al[buf][p][rb * 32]);
      } else {
        const int ib = idx - 16;
        const int p = ib >> 3, rb = (ib & 7) * 16;
        async_load16(W + (size_t)(n0 + rb + r4) * 1024 + kk + p * 32 + c4s,
                     &Bl[buf][p][rb * 32]);
      }
    }
  };

  stage(0, 0);
  for (int it = 0; it < 16; ++it) {
    const int buf = it & 1;
    __syncthreads();
    if (it < 15) stage(buf ^ 1, (it + 1) * 64);
#pragma unroll
    for (int kc = 0; kc < 2; ++kc) {
      h8 af[4], bf[4];
#pragma unroll
      for (int mi = 0; mi < 4; ++mi)
        af[mi] = *(const h8*)&Al[buf][kc][(wm0 + mi * 16 + ln) * 32 + qs8];
#pragma unroll
      for (int ni = 0; ni < 4; ++ni)
        bf[ni] = *(const h8*)&Bl[buf][kc][(wn0 + ni * 16 + ln) * 32 + qs8];
#pragma unroll
      for (int mi = 0; mi < 4; ++mi)
#pragma unroll
        for (int ni = 0; ni < 4; ++ni)
          acc[mi][ni] = __builtin_amdgcn_mfma_f32_16x16x32_f16(af[mi], bf[ni], acc[mi][ni], 0, 0, 0);
    }
  }

#pragma unroll
  for (int mi = 0; mi < 4; ++mi)
#pragma unroll
    for (int ni = 0; ni < 4; ++ni)
#pragma unroll
      for (int r = 0; r < 4; ++r) {
        const int row = m0 + wm0 + mi * 16 + quad * 4 + r;
        const int col = n0 + wn0 + ni * 16 + ln;
        const unsigned short v = f2h(acc[mi][ni][r]);
        if (isq) {
          qb[((size_t)row << 10) + col] = v;
        } else if (col < 256) {
          kb[(size_t)row * 256 + col] = v;
        } else {
          const int c2 = col - 256, gg = c2 >> 6, dd = c2 & 63;
          const int bb = row >> 11, t = row & 2047;
          vTb[((size_t)((bb * 4 + gg) * 64 + dd) << 11) + t] = v;
        }
      }
}

// ---------------------------------------------------------------- o projection (r12 + 3-way combine) + residual
__global__ __launch_bounds__(256) void o_gemm(const unsigned short* __restrict__ O0,
                                              const unsigned short* __restrict__ O1,
                                              const unsigned short* __restrict__ O2,
                                              const float* __restrict__ l0p,
                                              const float* __restrict__ l1p,
                                              const float* __restrict__ l2p,
                                              const unsigned short* __restrict__ wob,
                                              const float* __restrict__ x,
                                              float* __restrict__ out) {
  __shared__ unsigned short Al[2][2][128 * 32];
  __shared__ unsigned short Bl[2][2][128 * 32];
  __shared__ float Linv[16 * 128];
  const int tid = threadIdx.x;
  const int w = tid >> 6, l = tid & 63;
  const int quad = l >> 4, ln = l & 15;
  const int wm0 = (w >> 1) * 64, wn0 = (w & 1) * 64;
  const int r4 = l >> 2;
  const int c4s = (((l & 3) ^ ((l >> 3) & 3))) * 8;
  const int qs8 = (quad ^ ((l >> 1) & 3)) * 8;

  const int z = blockIdx.x;
  const int m0 = (((z >> 6) << 3) + (z & 7)) * 128;
  const int n0 = ((z >> 3) & 7) * 128;

  // Linv[h][r] = 1/(l0+l1+l2) for this block's 128 rows, all 16 heads
  {
    const int h = tid >> 4, r0 = (tid & 15) * 8;
#pragma unroll
    for (int i = 0; i < 8; ++i) {
      const int r = r0 + i;
      const size_t li = (size_t)(m0 + r) * 16 + h;
      Linv[h * 128 + r] = 1.0f / (l0p[li] + l1p[li] + l2p[li]);
    }
  }
  __syncthreads();

  const int srow = tid >> 3;       // 0..31
  const int sp = (tid >> 2) & 1;   // col-half
  const int ss = tid & 3;          // 16B slot

  auto stageA = [&](int buf, int kk) {
    const int h = kk >> 6;
#pragma unroll
    for (int ps = 0; ps < 4; ++ps) {
      const int row = ps * 32 + srow;
      const size_t gidx = (size_t)(m0 + row) * 1024 + kk + sp * 32 + ss * 8;
      h8 a0 = *(const h8*)&O0[gidx];
      h8 a1 = *(const h8*)&O1[gidx];
      h8 a2 = *(const h8*)&O2[gidx];
      const _Float16 lv = (_Float16)Linv[h * 128 + row];
      h8 sum = a0 + a1 + a2;
#pragma unroll
      for (int q2 = 0; q2 < 8; ++q2) sum[q2] *= lv;
      const int sl = ss ^ ((row >> 1) & 3);
      *(h8*)&Al[buf][sp][row * 32 + sl * 8] = sum;
    }
  };
  auto stageB = [&](int buf, int kk) {
#pragma unroll
    for (int j = 0; j < 4; ++j) {
      const int ib = w * 4 + j;
      const int p = ib >> 3, rb = (ib & 7) * 16;
      async_load16(wob + (size_t)(n0 + rb + r4) * 1024 + kk + p * 32 + c4s,
                   &Bl[buf][p][rb * 32]);
    }
  };

  f32x4 acc[4][4] = {};
  stageB(0, 0);
  stageA(0, 0);
  for (int it = 0; it < 16; ++it) {
    const int buf = it & 1;
    __syncthreads();
    if (it < 15) { stageB(buf ^ 1, (it + 1) * 64); stageA(buf ^ 1, (it + 1) * 64); }
#pragma unroll
    for (int kc = 0; kc < 2; ++kc) {
      h8 af[4], bf[4];
#pragma unroll
      for (int mi = 0; mi < 4; ++mi)
        af[mi] = *(const h8*)&Al[buf][kc][(wm0 + mi * 16 + ln) * 32 + qs8];
#pragma unroll
      for (int ni = 0; ni < 4; ++ni)
        bf[ni] = *(const h8*)&Bl[buf][kc][(wn0 + ni * 16 + ln) * 32 + qs8];
#pragma unroll
      for (int mi = 0; mi < 4; ++mi)
#pragma unroll
        for (int ni = 0; ni < 4; ++ni)
          acc[mi][ni] = __builtin_amdgcn_mfma_f32_16x16x32_f16(af[mi], bf[ni], acc[mi][ni], 0, 0, 0);
    }
  }

#pragma unroll
  for (int mi = 0; mi < 4; ++mi)
#pragma unroll
    for (int ni = 0; ni < 4; ++ni)
#pragma unroll
      for (int r = 0; r < 4; ++r) {
        const int row = m0 + wm0 + mi * 16 + quad * 4 + r;
        const int col = n0 + wn0 + ni * 16 + ln;
        const size_t idx = ((size_t)row << 10) + col;
        out[idx] = x[idx] + acc[mi][ni][r];
      }
}

// ---------------------------------------------------------------- flash attention (r16: T-split 3, spill-proof)
// r15's 81us failure was VGPR spill (VGPR 120->84, FETCH/WRITE +90MB scratch)
// from the runtime-guarded triple-buffer pipeline. r16 keeps the TLP goal
// (768 blocks = 3/CU = 12 waves/CU) with a spill-proof structure: DOUBLE
// buffer (32K LDS) + the r9/r12-proven drain-sync loop. Runtime nt (11/11/10)
// affects only the loop bound and one uniform guard; buffer select is an LDS
// address cndmask (never a VGPR-array index). Single body instantiation.
__global__ __launch_bounds__(256, 3) void flash_attn(const unsigned short* __restrict__ q,
                                                     const unsigned short* __restrict__ k,
                                                     const unsigned short* __restrict__ vT,
                                                     unsigned short* __restrict__ o0,
                                                     unsigned short* __restrict__ o1,
                                                     unsigned short* __restrict__ o2,
                                                     float* __restrict__ l0p,
                                                     float* __restrict__ l1p,
                                                     float* __restrict__ l2p) {
  __shared__ __align__(16) unsigned short Kl[2][64 * 64];  // [t][d] f16, swizzled
  __shared__ __align__(16) unsigned short Vl[2][64 * 64];  // [d][t] f16 (V^T), swizzled

  const int tid = threadIdx.x;
  const int w = tid >> 6, l = tid & 63;
  const int lq = l & 31, hi = l >> 5;
  const int r8 = l >> 3, c8 = l & 7;
  const int csw = (c8 ^ r8) * 8;  // staging source swizzle (u16 units)
  const int rsw = lq & 7;
  const int s0 = blockIdx.x * 256;
  const int h = blockIdx.y, g = h >> 2;
  const int zz = blockIdx.z;          // 0..5
  const int b = zz / 3, ts = zz - b * 3;
  const int nt = (ts == 2) ? 10 : 11; // tiles per part (11+11+10 = 32)
  const int tbase = ts * 704;         // 0, 704, 1408

  unsigned short* Opart = (ts == 0) ? o0 : (ts == 1) ? o1 : o2;
  float* lpart = (ts == 0) ? l0p : (ts == 1) ? l1p : l2p;

  // two q-rows per lane: q2 = 0,1
  size_t qrow[2];
  qrow[0] = (size_t)(b * 2048 + s0 + w * 64 + lq);
  qrow[1] = qrow[0] + 32;

  // Q B-fragments: lane holds Q[q=qrow[q2]][d = ks*16 + hi*8 + 0..7]
  h8 qf[2][4];
#pragma unroll
  for (int q2 = 0; q2 < 2; ++q2)
#pragma unroll
    for (int ks = 0; ks < 4; ++ks)
      qf[q2][ks] = *(const h8*)&q[(qrow[q2] << 10) + h * 64 + ks * 16 + hi * 8];

  // per-lane LDS byte offsets shared by ALL K/V fragment reads (j = k-slot)
  int aoff[4];
#pragma unroll
  for (int j = 0; j < 4; ++j)
    aoff[j] = (lq * 64 + (((2 * j + hi) ^ rsw)) * 8) * 2;

  f32x16 oacc[2][2] = {};  // [q2][dblk]: O^T[d=dblk*32+crow(r,hi)][q=lq]
  float lsum[2] = {0.0f, 0.0f};

  const unsigned short* kbase = k + ((size_t)(b * 2048)) * 256 + g * 64;
  const unsigned short* vbase = vT + (((size_t)(b * 4 + g) * 64) << 11);

  const hh2 one2 = {(__fp16)1.0f, (__fp16)1.0f};

  auto stage = [&](int sb, int t0) {
#pragma unroll
    for (int j = 0; j < 2; ++j) {
      const int idx = w * 2 + j;  // 0..7 row-group of 8
      async_load16(kbase + (size_t)(t0 + idx * 8 + r8) * 256 + csw,
                   &Kl[sb][idx * 512]);
      async_load16(vbase + (((size_t)(idx * 8 + r8)) << 11) + t0 + csw,
                   &Vl[sb][idx * 512]);
    }
  };

  stage(0, tbase);
  for (int it = 0; it < nt; ++it) {
    const int buf = it & 1;
    __syncthreads();  // drains vmcnt -> buf's tile landed; all waves done with buf^1
    if (it + 1 < nt) stage(buf ^ 1, tbase + (it + 1) * 64);

    const unsigned short* KB = &Kl[buf][0];
    const unsigned short* VB = &Vl[buf][0];

#pragma unroll
    for (int TH = 0; TH < 2; ++TH) {
      h8 kf[4];
#pragma unroll
      for (int ks = 0; ks < 4; ++ks)
        kf[ks] = *(const h8*)((const char*)KB + TH * 4096 + aoff[ks]);
      f32x16 st0 = {}, st1 = {};
      __builtin_amdgcn_s_setprio(1);
#pragma unroll
      for (int ks = 0; ks < 4; ++ks) {
        st0 = __builtin_amdgcn_mfma_f32_32x32x16_f16(kf[ks], qf[0][ks], st0, 0, 0, 0);
        st1 = __builtin_amdgcn_mfma_f32_32x32x16_f16(kf[ks], qf[1][ks], st1, 0, 0, 0);
      }
      __builtin_amdgcn_s_setprio(0);
      unsigned int w0_[8], w1_[8];
#pragma unroll
      for (int j = 0; j < 8; ++j) {
        union { hh2 h2; unsigned int u; } pk0, pk1;
        pk0.h2 = __builtin_amdgcn_cvt_pkrtz(__builtin_amdgcn_exp2f(st0[2 * j]),
                                            __builtin_amdgcn_exp2f(st0[2 * j + 1]));
        pk1.h2 = __builtin_amdgcn_cvt_pkrtz(__builtin_amdgcn_exp2f(st1[2 * j]),
                                            __builtin_amdgcn_exp2f(st1[2 * j + 1]));
        lsum[0] = __builtin_amdgcn_fdot2(pk0.h2, one2, lsum[0], false);
        lsum[1] = __builtin_amdgcn_fdot2(pk1.h2, one2, lsum[1], false);
        w0_[j] = pk0.u; w1_[j] = pk1.u;
      }
      h8 pf0[2], pf1[2];
      {
        unsigned int a0 = w0_[0], b0 = w0_[2]; pl32swap(a0, b0);
        unsigned int a1 = w0_[1], b1 = w0_[3]; pl32swap(a1, b1);
        unsigned int a4 = w0_[4], b4 = w0_[6]; pl32swap(a4, b4);
        unsigned int a5 = w0_[5], b5 = w0_[7]; pl32swap(a5, b5);
        union { unsigned int u[4]; h8 v; } f0, f1;
        f0.u[0] = a0; f0.u[1] = a1; f0.u[2] = b0; f0.u[3] = b1;
        f1.u[0] = a4; f1.u[1] = a5; f1.u[2] = b4; f1.u[3] = b5;
        pf0[0] = f0.v; pf0[1] = f1.v;
        unsigned int c0 = w1_[0], d0 = w1_[2]; pl32swap(c0, d0);
        unsigned int c1 = w1_[1], d1 = w1_[3]; pl32swap(c1, d1);
        unsigned int c4 = w1_[4], d4 = w1_[6]; pl32swap(c4, d4);
        unsigned int c5 = w1_[5], d5 = w1_[7]; pl32swap(c5, d5);
        union { unsigned int u[4]; h8 v; } f2, f3;
        f2.u[0] = c0; f2.u[1] = c1; f2.u[2] = d0; f2.u[3] = d1;
        f3.u[0] = c4; f3.u[1] = c5; f3.u[2] = d4; f3.u[3] = d5;
        pf1[0] = f2.v; pf1[1] = f3.v;
      }
      __builtin_amdgcn_s_setprio(1);
#pragma unroll
      for (int cc = 0; cc < 2; ++cc) {
        const int c = TH * 2 + cc;
        h8 v0 = *(const h8*)((const char*)VB + aoff[c]);
        h8 v1 = *(const h8*)((const char*)VB + 4096 + aoff[c]);
        oacc[0][0] = __builtin_amdgcn_mfma_f32_32x32x16_f16(v0, pf0[cc], oacc[0][0], 0, 0, 0);
        oacc[1][0] = __builtin_amdgcn_mfma_f32_32x32x16_f16(v0, pf1[cc], oacc[1][0], 0, 0, 0);
        oacc[0][1] = __builtin_amdgcn_mfma_f32_32x32x16_f16(v1, pf0[cc], oacc[0][1], 0, 0, 0);
        oacc[1][1] = __builtin_amdgcn_mfma_f32_32x32x16_f16(v1, pf1[cc], oacc[1][1], 0, 0, 0);
      }
      __builtin_amdgcn_s_setprio(0);
    }
  }

  // lane l covers half the t's for q=lq; partner l^32 the other half
#pragma unroll
  for (int q2 = 0; q2 < 2; ++q2) {
    float ls = lsum[q2];
    ls += __shfl_xor(ls, 32);
    if (l < 32) lpart[qrow[q2] * 16 + h] = ls;
#pragma unroll
    for (int dblk = 0; dblk < 2; ++dblk)
#pragma unroll
      for (int qd = 0; qd < 4; ++qd) {
        ushort4 o;
        o.x = f2h(oacc[q2][dblk][qd * 4 + 0]);
        o.y = f2h(oacc[q2][dblk][qd * 4 + 1]);
        o.z = f2h(oacc[q2][dblk][qd * 4 + 2]);
        o.w = f2h(oacc[q2][dblk][qd * 4 + 3]);
        // d = dblk*32 + qd*8 + hi*4 + 0..3
        *(ushort4*)&Opart[(qrow[q2] << 10) + h * 64 + dblk * 32 + qd * 8 + hi * 4] = o;
      }
  }
}

// ---------------------------------------------------------------- launch
extern "C" void kernel_launch(void* const* d_in, const int* in_sizes, int n_in,
                              void* d_out, int out_size, void* d_ws, size_t ws_size,
                              hipStream_t stream) {
  const float* x   = (const float*)d_in[0];
  const float* kv  = (const float*)d_in[1];
  const float* wq  = (const float*)d_in[2];
  const float* wk  = (const float*)d_in[3];
  const float* wv  = (const float*)d_in[4];
  const float* wo  = (const float*)d_in[5];
  const float* gq  = (const float*)d_in[6];
  const float* gkv = (const float*)d_in[7];

  char* ws = (char*)d_ws;
  unsigned short* xn   = (unsigned short*)(ws);              // 0-8M   xn -> Opart0
  unsigned short* kvn  = (unsigned short*)(ws + 8388608);    // 8-16M  kvn -> Opart1
  unsigned short* qb   = (unsigned short*)(ws + 16777216);   // 16-24M q f16 (pre-scaled)
  unsigned short* kb   = (unsigned short*)(ws + 25165824);   // 24-26M K f16 (4096x256)
  unsigned short* vTb  = (unsigned short*)(ws + 27262976);   // 26-28M V^T f16
  unsigned short* O2   = (unsigned short*)(ws + 29360128);   // 28-36M (the former hole)
  unsigned short* wqb  = (unsigned short*)(ws + 37748736);   // 36-38M wq f16 -> l0p/l1p/l2p
  unsigned short* wkvb = (unsigned short*)(ws + 39845888);   // 38-39M [wk;wv] f16
  unsigned short* wob  = (unsigned short*)(ws + 40894464);   // 39-41M wo f16
  unsigned short* Opart0 = xn;
  unsigned short* Opart1 = kvn;
  float* l0p = (float*)wqb;
  float* l1p = (float*)(ws + 37748736 + 262144);
  float* l2p = (float*)(ws + 37748736 + 524288);

  const float qscale = 0.18033688011112042f;  // (1/8) * log2(e)

  prep<<<2688, 256, 0, stream>>>(x, kv, wq, wk, wv, wo, gq, gkv,
                                 wqb, wkvb, wob, xn, kvn, qscale);

  // fused q + kv projections (128x128 tiles, dbuf, swizzled, XCD-mapped)
  proj_gemm<<<384, 256, 0, stream>>>(xn, kvn, wqb, wkvb, qb, kb, vTb);

  // flash: 256 Q-rows/block (64/wave), T-split 3 -> 768 blocks = 3/CU (dbuf)
  flash_attn<<<dim3(8, 16, 6), 256, 0, stream>>>(qb, kb, vTb, Opart0, Opart1, O2,
                                                 l0p, l1p, l2p);

  // o projection (128x128) with fused 3-way T-split combine + residual
  o_gemm<<<256, 256, 0, stream>>>(Opart0, Opart1, O2, l0p, l1p, l2p, wob, x, (float*)d_out);
}

// Round 10
// 190.651 us; speedup vs baseline: 1.3486x; 1.0407x over previous
//
#include <hip/hip_runtime.h>

#define DEV __device__ __forceinline__

typedef __attribute__((ext_vector_type(8))) _Float16 h8;
typedef __attribute__((ext_vector_type(4))) float f32x4;
typedef __attribute__((ext_vector_type(16))) float f32x16;
typedef __fp16 __attribute__((ext_vector_type(2))) hh2;

DEV unsigned short f2h(float f) {
  union { _Float16 h[2]; unsigned short u[2]; } v;
  v.h[0] = (_Float16)f;
  return v.u[0];
}

DEV void async_load16(const void* g, void* l) {
  __builtin_amdgcn_global_load_lds(
      (const __attribute__((address_space(1))) void*)g,
      (__attribute__((address_space(3))) void*)l,
      16, 0, 0);
}

// v_permlane32_swap_b32: a.row1 <-> b.row0 (exchanges the two 32-lane halves
// across two VGPRs). Both outputs are used (m214 T12 recipe).
DEV void pl32swap(unsigned int& a, unsigned int& b) {
  asm("v_permlane32_swap_b32 %0, %1" : "+v"(a), "+v"(b));
}

// LDS panel XOR swizzle: row r, 16B col-block c stored at slot c ^ ((r>>1)&3);
// fragment reads use qs8 = (quad ^ ((ln>>1)&3))*8.

// ---------------------------------------------------------------- prep (r12): wave-per-row rmsnorm
__global__ __launch_bounds__(256) void prep(const float* __restrict__ x,
                                            const float* __restrict__ kv,
                                            const float* __restrict__ wq,
                                            const float* __restrict__ wk,
                                            const float* __restrict__ wv,
                                            const float* __restrict__ wo,
                                            const float* __restrict__ gq,
                                            const float* __restrict__ gkv,
                                            unsigned short* __restrict__ wqb,
                                            unsigned short* __restrict__ wkvb,
                                            unsigned short* __restrict__ wob,
                                            unsigned short* __restrict__ xn,
                                            unsigned short* __restrict__ kvn,
                                            float qscale) {
  const int b = blockIdx.x, tid = threadIdx.x;
  if (b < 640) {
    // weight cast: 4096 floats per block
    const float* src;
    unsigned short* dst;
    float sc = 1.0f;
    int base;
    if (b < 256) { src = wq; dst = wqb; sc = qscale; base = b; }
    else if (b < 320) { src = wk; dst = wkvb; base = b - 256; }
    else if (b < 384) { src = wv; dst = wkvb + 262144; base = b - 320; }
    else { src = wo; dst = wob; base = b - 384; }
#pragma unroll
    for (int j = 0; j < 4; ++j) {
      const int i = base * 4096 + j * 1024 + tid * 4;
      float4 v = *(const float4*)&src[i];
      ushort4 o;
      o.x = f2h(v.x * sc); o.y = f2h(v.y * sc);
      o.z = f2h(v.z * sc); o.w = f2h(v.w * sc);
      *(ushort4*)&dst[i] = o;
    }
    return;
  }
  // rmsnorm: one wave per 1024-elem row
  const int w = tid >> 6, l = tid & 63;
  int row = (b - 640) * 4 + w;
  const float* src;
  const float* g;
  unsigned short* dst;
  if (row < 4096) { src = x; g = gq; dst = xn; }
  else { row -= 4096; src = kv; g = gkv; dst = kvn; }
  const float* xr = src + (size_t)row * 1024;
  float4 v[4];
  float ss = 0.0f;
#pragma unroll
  for (int i = 0; i < 4; ++i) {
    v[i] = *(const float4*)&xr[i * 256 + l * 4];
    ss += v[i].x * v[i].x + v[i].y * v[i].y + v[i].z * v[i].z + v[i].w * v[i].w;
  }
  ss += __shfl_xor(ss, 32); ss += __shfl_xor(ss, 16);
  ss += __shfl_xor(ss, 8);  ss += __shfl_xor(ss, 4);
  ss += __shfl_xor(ss, 2);  ss += __shfl_xor(ss, 1);
  const float inv = rsqrtf(ss * (1.0f / 1024.0f) + 1e-5f);
#pragma unroll
  for (int i = 0; i < 4; ++i) {
    float4 gv = *(const float4*)&g[i * 256 + l * 4];
    ushort4 o;
    o.x = f2h(v[i].x * inv * gv.x); o.y = f2h(v[i].y * inv * gv.y);
    o.z = f2h(v[i].z * inv * gv.z); o.w = f2h(v[i].w * inv * gv.w);
    *(ushort4*)&dst[(size_t)row * 1024 + i * 256 + l * 4] = o;
  }
}

// ---------------------------------------------------------------- fused q + kv projections (r12 exact)
// 128x128 tile, 4 waves x 64x64, BK=64, 2-phase dbuf, swizzled, XCD-mapped.
__global__ __launch_bounds__(256, 2) void proj_gemm(const unsigned short* __restrict__ xn,
                                                    const unsigned short* __restrict__ kvn,
                                                    const unsigned short* __restrict__ wqb,
                                                    const unsigned short* __restrict__ wkvb,
                                                    unsigned short* __restrict__ qb,
                                                    unsigned short* __restrict__ kb,
                                                    unsigned short* __restrict__ vTb) {
  __shared__ unsigned short Al[2][2][128 * 32];
  __shared__ unsigned short Bl[2][2][128 * 32];
  const int tid = threadIdx.x;
  const int w = tid >> 6, l = tid & 63;
  const int quad = l >> 4, ln = l & 15;
  const int wm0 = (w >> 1) * 64, wn0 = (w & 1) * 64;
  const int r4 = l >> 2;
  const int c4s = (((l & 3) ^ ((l >> 3) & 3))) * 8;
  const int qs8 = (quad ^ ((l >> 1) & 3)) * 8;

  int z = blockIdx.x;
  const unsigned short *A, *W;
  int m0, n0, isq;
  if (z < 256) {
    A = xn; W = wqb; isq = 1;
    m0 = (((z >> 6) << 3) + (z & 7)) * 128;
    n0 = ((z >> 3) & 7) * 128;
  } else {
    z -= 256; A = kvn; W = wkvb; isq = 0;
    m0 = (((z >> 5) << 3) + (z & 7)) * 128;
    n0 = ((z >> 3) & 3) * 128;
  }

  f32x4 acc[4][4] = {};

  auto stage = [&](int buf, int kk) {
#pragma unroll
    for (int j = 0; j < 8; ++j) {
      const int idx = w * 8 + j;
      if (idx < 16) {
        const int p = idx >> 3, rb = (idx & 7) * 16;
        async_load16(A + (size_t)(m0 + rb + r4) * 1024 + kk + p * 32 + c4s,
                     &Al[buf][p][rb * 32]);
      } else {
        const int ib = idx - 16;
        const int p = ib >> 3, rb = (ib & 7) * 16;
        async_load16(W + (size_t)(n0 + rb + r4) * 1024 + kk + p * 32 + c4s,
                     &Bl[buf][p][rb * 32]);
      }
    }
  };

  stage(0, 0);
  for (int it = 0; it < 16; ++it) {
    const int buf = it & 1;
    __syncthreads();
    if (it < 15) stage(buf ^ 1, (it + 1) * 64);
#pragma unroll
    for (int kc = 0; kc < 2; ++kc) {
      h8 af[4], bf[4];
#pragma unroll
      for (int mi = 0; mi < 4; ++mi)
        af[mi] = *(const h8*)&Al[buf][kc][(wm0 + mi * 16 + ln) * 32 + qs8];
#pragma unroll
      for (int ni = 0; ni < 4; ++ni)
        bf[ni] = *(const h8*)&Bl[buf][kc][(wn0 + ni * 16 + ln) * 32 + qs8];
#pragma unroll
      for (int mi = 0; mi < 4; ++mi)
#pragma unroll
        for (int ni = 0; ni < 4; ++ni)
          acc[mi][ni] = __builtin_amdgcn_mfma_f32_16x16x32_f16(af[mi], bf[ni], acc[mi][ni], 0, 0, 0);
    }
  }

#pragma unroll
  for (int mi = 0; mi < 4; ++mi)
#pragma unroll
    for (int ni = 0; ni < 4; ++ni)
#pragma unroll
      for (int r = 0; r < 4; ++r) {
        const int row = m0 + wm0 + mi * 16 + quad * 4 + r;
        const int col = n0 + wn0 + ni * 16 + ln;
        const unsigned short v = f2h(acc[mi][ni][r]);
        if (isq) {
          qb[((size_t)row << 10) + col] = v;
        } else if (col < 256) {
          kb[(size_t)row * 256 + col] = v;
        } else {
          const int c2 = col - 256, gg = c2 >> 6, dd = c2 & 63;
          const int bb = row >> 11, t = row & 2047;
          vTb[((size_t)((bb * 4 + gg) * 64 + dd) << 11) + t] = v;
        }
      }
}

// ---------------------------------------------------------------- o projection (r12 exact) + residual
__global__ __launch_bounds__(256) void o_gemm(const unsigned short* __restrict__ O0,
                                              const unsigned short* __restrict__ O1,
                                              const float* __restrict__ l0p,
                                              const float* __restrict__ l1p,
                                              const unsigned short* __restrict__ wob,
                                              const float* __restrict__ x,
                                              float* __restrict__ out) {
  __shared__ unsigned short Al[2][2][128 * 32];
  __shared__ unsigned short Bl[2][2][128 * 32];
  __shared__ float Linv[16 * 128];
  const int tid = threadIdx.x;
  const int w = tid >> 6, l = tid & 63;
  const int quad = l >> 4, ln = l & 15;
  const int wm0 = (w >> 1) * 64, wn0 = (w & 1) * 64;
  const int r4 = l >> 2;
  const int c4s = (((l & 3) ^ ((l >> 3) & 3))) * 8;
  const int qs8 = (quad ^ ((l >> 1) & 3)) * 8;

  const int z = blockIdx.x;
  const int m0 = (((z >> 6) << 3) + (z & 7)) * 128;
  const int n0 = ((z >> 3) & 7) * 128;

  // Linv[h][r] = 1/(l0+l1) for this block's 128 rows, all 16 heads
  {
    const int h = tid >> 4, r0 = (tid & 15) * 8;
#pragma unroll
    for (int i = 0; i < 8; ++i) {
      const int r = r0 + i;
      const size_t li = (size_t)(m0 + r) * 16 + h;
      Linv[h * 128 + r] = 1.0f / (l0p[li] + l1p[li]);
    }
  }
  __syncthreads();

  const int srow = tid >> 3;       // 0..31
  const int sp = (tid >> 2) & 1;   // col-half
  const int ss = tid & 3;          // 16B slot

  auto stageA = [&](int buf, int kk) {
    const int h = kk >> 6;
#pragma unroll
    for (int ps = 0; ps < 4; ++ps) {
      const int row = ps * 32 + srow;
      const size_t gidx = (size_t)(m0 + row) * 1024 + kk + sp * 32 + ss * 8;
      h8 a0 = *(const h8*)&O0[gidx];
      h8 a1 = *(const h8*)&O1[gidx];
      const _Float16 lv = (_Float16)Linv[h * 128 + row];
      h8 sum = a0 + a1;
#pragma unroll
      for (int q2 = 0; q2 < 8; ++q2) sum[q2] *= lv;
      const int sl = ss ^ ((row >> 1) & 3);
      *(h8*)&Al[buf][sp][row * 32 + sl * 8] = sum;
    }
  };
  auto stageB = [&](int buf, int kk) {
#pragma unroll
    for (int j = 0; j < 4; ++j) {
      const int ib = w * 4 + j;
      const int p = ib >> 3, rb = (ib & 7) * 16;
      async_load16(wob + (size_t)(n0 + rb + r4) * 1024 + kk + p * 32 + c4s,
                   &Bl[buf][p][rb * 32]);
    }
  };

  f32x4 acc[4][4] = {};
  stageB(0, 0);
  stageA(0, 0);
  for (int it = 0; it < 16; ++it) {
    const int buf = it & 1;
    __syncthreads();
    if (it < 15) { stageB(buf ^ 1, (it + 1) * 64); stageA(buf ^ 1, (it + 1) * 64); }
#pragma unroll
    for (int kc = 0; kc < 2; ++kc) {
      h8 af[4], bf[4];
#pragma unroll
      for (int mi = 0; mi < 4; ++mi)
        af[mi] = *(const h8*)&Al[buf][kc][(wm0 + mi * 16 + ln) * 32 + qs8];
#pragma unroll
      for (int ni = 0; ni < 4; ++ni)
        bf[ni] = *(const h8*)&Bl[buf][kc][(wn0 + ni * 16 + ln) * 32 + qs8];
#pragma unroll
      for (int mi = 0; mi < 4; ++mi)
#pragma unroll
        for (int ni = 0; ni < 4; ++ni)
          acc[mi][ni] = __builtin_amdgcn_mfma_f32_16x16x32_f16(af[mi], bf[ni], acc[mi][ni], 0, 0, 0);
    }
  }

#pragma unroll
  for (int mi = 0; mi < 4; ++mi)
#pragma unroll
    for (int ni = 0; ni < 4; ++ni)
#pragma unroll
      for (int r = 0; r < 4; ++r) {
        const int row = m0 + wm0 + mi * 16 + quad * 4 + r;
        const int col = n0 + wn0 + ni * 16 + ln;
        const size_t idx = ((size_t)row << 10) + col;
        out[idx] = x[idx] + acc[mi][ni][r];
      }
}

// ---------------------------------------------------------------- flash attention (r11 exact: best measured 47.6us)
// 64 q-rows/wave: same kf/v fragments feed 32 MFMAs; counted-vmcnt
// triple-buffer (never vmcnt(0) mid-loop); in-register P via cvt_pk+permlane.
__global__ __launch_bounds__(256, 2) void flash_attn(const unsigned short* __restrict__ q,
                                                     const unsigned short* __restrict__ k,
                                                     const unsigned short* __restrict__ vT,
                                                     unsigned short* __restrict__ o0,
                                                     unsigned short* __restrict__ o1,
                                                     float* __restrict__ l0p,
                                                     float* __restrict__ l1p) {
  __shared__ __align__(16) unsigned short Kl[3][64 * 64];  // [t][d] f16, swizzled
  __shared__ __align__(16) unsigned short Vl[3][64 * 64];  // [d][t] f16 (V^T), swizzled

  const int tid = threadIdx.x;
  const int w = tid >> 6, l = tid & 63;
  const int lq = l & 31, hi = l >> 5;
  const int r8 = l >> 3, c8 = l & 7;
  const int csw = (c8 ^ r8) * 8;  // staging source swizzle (u16 units)
  const int rsw = lq & 7;
  const int s0 = blockIdx.x * 256;
  const int h = blockIdx.y, g = h >> 2;
  const int b = blockIdx.z >> 1, ts = blockIdx.z & 1;
  const int tbase = ts << 10;

  unsigned short* Opart = ts ? o1 : o0;
  float* lpart = ts ? l1p : l0p;

  // two q-rows per lane: q2 = 0,1
  size_t qrow[2];
  qrow[0] = (size_t)(b * 2048 + s0 + w * 64 + lq);
  qrow[1] = qrow[0] + 32;

  // Q B-fragments: lane holds Q[q=qrow[q2]][d = ks*16 + hi*8 + 0..7]
  h8 qf[2][4];
#pragma unroll
  for (int q2 = 0; q2 < 2; ++q2)
#pragma unroll
    for (int ks = 0; ks < 4; ++ks)
      qf[q2][ks] = *(const h8*)&q[(qrow[q2] << 10) + h * 64 + ks * 16 + hi * 8];
  // drain the q loads so the manual vmcnt bookkeeping below starts from 0
  asm volatile("s_waitcnt vmcnt(0)" ::: "memory");

  // per-lane LDS byte offsets shared by ALL K/V fragment reads (j = k-slot)
  int aoff[4];
#pragma unroll
  for (int j = 0; j < 4; ++j)
    aoff[j] = (lq * 64 + (((2 * j + hi) ^ rsw)) * 8) * 2;

  f32x16 oacc[2][2] = {};  // [q2][dblk]: O^T[d=dblk*32+crow(r,hi)][q=lq]
  float lsum[2] = {0.0f, 0.0f};

  const unsigned short* kbase = k + ((size_t)(b * 2048)) * 256 + g * 64;
  const unsigned short* vbase = vT + (((size_t)(b * 4 + g) * 64) << 11);

  const hh2 one2 = {(__fp16)1.0f, (__fp16)1.0f};

  auto stage = [&](int sb, int t0) {
#pragma unroll
    for (int j = 0; j < 2; ++j) {
      const int idx = w * 2 + j;  // 0..7 row-group of 8
      async_load16(kbase + (size_t)(t0 + idx * 8 + r8) * 256 + csw,
                   &Kl[sb][idx * 512]);
      async_load16(vbase + (((size_t)(idx * 8 + r8)) << 11) + t0 + csw,
                   &Vl[sb][idx * 512]);
    }
  };

#define FA_SYNC(N)                                                   \
  do {                                                               \
    asm volatile("s_waitcnt vmcnt(" #N ")" ::: "memory");            \
    __builtin_amdgcn_s_barrier();                                    \
    __builtin_amdgcn_sched_barrier(0);                               \
  } while (0)

// one t-half (32 t's) of one tile: shared kf feeds both q2 QK chains; shared
// v frags feed both q2 PV chains. All indices compile-time after unroll.
#define FA_HALF(CB, TH)                                                        \
  {                                                                            \
    h8 kf[4];                                                                  \
    _Pragma("unroll")                                                          \
    for (int ks = 0; ks < 4; ++ks)                                             \
      kf[ks] = *(const h8*)((const char*)&Kl[CB][(TH) * 2048] + aoff[ks]);     \
    f32x16 st0 = {}, st1 = {};                                                 \
    __builtin_amdgcn_s_setprio(1);                                             \
    _Pragma("unroll")                                                          \
    for (int ks = 0; ks < 4; ++ks) {                                           \
      st0 = __builtin_amdgcn_mfma_f32_32x32x16_f16(kf[ks], qf[0][ks], st0, 0, 0, 0); \
      st1 = __builtin_amdgcn_mfma_f32_32x32x16_f16(kf[ks], qf[1][ks], st1, 0, 0, 0); \
    }                                                                          \
    __builtin_amdgcn_s_setprio(0);                                             \
    unsigned int w0_[8], w1_[8];                                               \
    _Pragma("unroll")                                                          \
    for (int j = 0; j < 8; ++j) {                                              \
      union { hh2 h2; unsigned int u; } pk0, pk1;                              \
      pk0.h2 = __builtin_amdgcn_cvt_pkrtz(__builtin_amdgcn_exp2f(st0[2 * j]),  \
                                          __builtin_amdgcn_exp2f(st0[2 * j + 1])); \
      pk1.h2 = __builtin_amdgcn_cvt_pkrtz(__builtin_amdgcn_exp2f(st1[2 * j]),  \
                                          __builtin_amdgcn_exp2f(st1[2 * j + 1])); \
      lsum[0] = __builtin_amdgcn_fdot2(pk0.h2, one2, lsum[0], false);          \
      lsum[1] = __builtin_amdgcn_fdot2(pk1.h2, one2, lsum[1], false);          \
      w0_[j] = pk0.u; w1_[j] = pk1.u;                                          \
    }                                                                          \
    h8 pf0[2], pf1[2];                                                         \
    {                                                                          \
      unsigned int a0 = w0_[0], b0 = w0_[2]; pl32swap(a0, b0);                 \
      unsigned int a1 = w0_[1], b1 = w0_[3]; pl32swap(a1, b1);                 \
      unsigned int a4 = w0_[4], b4 = w0_[6]; pl32swap(a4, b4);                 \
      unsigned int a5 = w0_[5], b5 = w0_[7]; pl32swap(a5, b5);                 \
      union { unsigned int u[4]; h8 v; } f0, f1;                               \
      f0.u[0] = a0; f0.u[1] = a1; f0.u[2] = b0; f0.u[3] = b1;                  \
      f1.u[0] = a4; f1.u[1] = a5; f1.u[2] = b4; f1.u[3] = b5;                  \
      pf0[0] = f0.v; pf0[1] = f1.v;                                            \
      unsigned int c0 = w1_[0], d0 = w1_[2]; pl32swap(c0, d0);                 \
      unsigned int c1 = w1_[1], d1 = w1_[3]; pl32swap(c1, d1);                 \
      unsigned int c4 = w1_[4], d4 = w1_[6]; pl32swap(c4, d4);                 \
      unsigned int c5 = w1_[5], d5 = w1_[7]; pl32swap(c5, d5);                 \
      union { unsigned int u[4]; h8 v; } f2, f3;                               \
      f2.u[0] = c0; f2.u[1] = c1; f2.u[2] = d0; f2.u[3] = d1;                  \
      f3.u[0] = c4; f3.u[1] = c5; f3.u[2] = d4; f3.u[3] = d5;                  \
      pf1[0] = f2.v; pf1[1] = f3.v;                                            \
    }                                                                          \
    __builtin_amdgcn_s_setprio(1);                                             \
    _Pragma("unroll")                                                          \
    for (int cc = 0; cc < 2; ++cc) {                                           \
      const int c = (TH) * 2 + cc;                                             \
      h8 v0 = *(const h8*)((const char*)&Vl[CB][0] + aoff[c]);                 \
      h8 v1 = *(const h8*)((const char*)&Vl[CB][2048] + aoff[c]);              \
      oacc[0][0] = __builtin_amdgcn_mfma_f32_32x32x16_f16(v0, pf0[cc], oacc[0][0], 0, 0, 0); \
      oacc[1][0] = __builtin_amdgcn_mfma_f32_32x32x16_f16(v0, pf1[cc], oacc[1][0], 0, 0, 0); \
      oacc[0][1] = __builtin_amdgcn_mfma_f32_32x32x16_f16(v1, pf0[cc], oacc[0][1], 0, 0, 0); \
      oacc[1][1] = __builtin_amdgcn_mfma_f32_32x32x16_f16(v1, pf1[cc], oacc[1][1], 0, 0, 0); \
    }                                                                          \
    __builtin_amdgcn_s_setprio(0);                                             \
  }

#define FA_BODY(CB) { FA_HALF(CB, 0) FA_HALF(CB, 1) }

  // prologue: two tiles in flight
  stage(0, tbase);
  stage(1, tbase + 64);

  // main: t = 0..14 (vmcnt(4) uniform: tile t+1's 4 loads may stay in flight)
  for (int tt = 0; tt < 15; tt += 3) {
    FA_SYNC(4);
    stage(2, tbase + (tt + 2) * 64);
    FA_BODY(0);
    FA_SYNC(4);
    stage(0, tbase + (tt + 3) * 64);
    FA_BODY(1);
    FA_SYNC(4);
    if (tt + 4 < 16) stage(1, tbase + (tt + 4) * 64);
    FA_BODY(2);
  }
  // t = 15 (buffer 0)
  FA_SYNC(0);
  FA_BODY(0);

#undef FA_BODY
#undef FA_HALF
#undef FA_SYNC

  // lane l covers half the t's for q=lq; partner l^32 the other half
#pragma unroll
  for (int q2 = 0; q2 < 2; ++q2) {
    float ls = lsum[q2];
    ls += __shfl_xor(ls, 32);
    if (l < 32) lpart[qrow[q2] * 16 + h] = ls;
#pragma unroll
    for (int dblk = 0; dblk < 2; ++dblk)
#pragma unroll
      for (int qd = 0; qd < 4; ++qd) {
        ushort4 o;
        o.x = f2h(oacc[q2][dblk][qd * 4 + 0]);
        o.y = f2h(oacc[q2][dblk][qd * 4 + 1]);
        o.z = f2h(oacc[q2][dblk][qd * 4 + 2]);
        o.w = f2h(oacc[q2][dblk][qd * 4 + 3]);
        // d = dblk*32 + qd*8 + hi*4 + 0..3
        *(ushort4*)&Opart[(qrow[q2] << 10) + h * 64 + dblk * 32 + qd * 8 + hi * 4] = o;
      }
  }
}

// ---------------------------------------------------------------- launch
extern "C" void kernel_launch(void* const* d_in, const int* in_sizes, int n_in,
                              void* d_out, int out_size, void* d_ws, size_t ws_size,
                              hipStream_t stream) {
  const float* x   = (const float*)d_in[0];
  const float* kv  = (const float*)d_in[1];
  const float* wq  = (const float*)d_in[2];
  const float* wk  = (const float*)d_in[3];
  const float* wv  = (const float*)d_in[4];
  const float* wo  = (const float*)d_in[5];
  const float* gq  = (const float*)d_in[6];
  const float* gkv = (const float*)d_in[7];

  char* ws = (char*)d_ws;
  unsigned short* xn   = (unsigned short*)(ws);              // 0-8M   xn -> Opart0
  unsigned short* kvn  = (unsigned short*)(ws + 8388608);    // 8-16M  kvn -> Opart1
  unsigned short* qb   = (unsigned short*)(ws + 16777216);   // 16-24M q f16 (pre-scaled)
  unsigned short* kb   = (unsigned short*)(ws + 25165824);   // 24-26M K f16 (4096x256)
  unsigned short* vTb  = (unsigned short*)(ws + 27262976);   // 26-28M V^T f16
  unsigned short* wqb  = (unsigned short*)(ws + 37748736);   // 36-38M wq f16 -> l0p/l1p
  unsigned short* wkvb = (unsigned short*)(ws + 39845888);   // 38-39M [wk;wv] f16
  unsigned short* wob  = (unsigned short*)(ws + 40894464);   // 39-41M wo f16
  unsigned short* Opart0 = xn;
  unsigned short* Opart1 = kvn;
  float* l0p = (float*)wqb;
  float* l1p = (float*)(ws + 37748736 + 262144);

  const float qscale = 0.18033688011112042f;  // (1/8) * log2(e)

  prep<<<2688, 256, 0, stream>>>(x, kv, wq, wk, wv, wo, gq, gkv,
                                 wqb, wkvb, wob, xn, kvn, qscale);

  // fused q + kv projections (128x128 tiles, dbuf, swizzled, XCD-mapped)
  proj_gemm<<<384, 256, 0, stream>>>(xn, kvn, wqb, wkvb, qb, kb, vTb);

  // flash: 256 Q-rows/block (64/wave), T-split 2 -> 512 blocks = 2/CU
  flash_attn<<<dim3(8, 16, 4), 256, 0, stream>>>(qb, kb, vTb, Opart0, Opart1, l0p, l1p);

  // o projection (128x128) with fused T-split combine + residual
  o_gemm<<<256, 256, 0, stream>>>(Opart0, Opart1, l0p, l1p, wob, x, (float*)d_out);
}